// Round 6
// baseline (6224.493 us; speedup 1.0000x reference)
//
#include <hip/hip_runtime.h>
#include <hip/hip_bf16.h>

// x: (1,32,32,64,64)  conv1 -> (64,33,64,64)  conv2 -> (64,34,64,64) -> slice 32
// row convention: r = z*4096 + n, n = y*64+x. Mamba section chunked 4x over n.
// DTYPE-ADAPTIVE: k_detect classifies raw inputs as f32 (flag=1) or bf16 (flag=0);
// all raw-input reads and the residual/output path branch on the flag.
#define NTHREADS 256

__device__ __forceinline__ float bf2f(__hip_bfloat16 v) { return __bfloat162float(v); }
__device__ __forceinline__ __hip_bfloat16 f2bf(float v) { return __float2bfloat16(v); }
__device__ __forceinline__ float b2f_lo(unsigned int p) { return __uint_as_float(p << 16); }
__device__ __forceinline__ float b2f_hi(unsigned int p) { return __uint_as_float(p & 0xffff0000u); }
__device__ __forceinline__ float sigm(float x) { return 1.f / (1.f + __expf(-x)); }
__device__ __forceinline__ float leaky(float x) { return x > 0.f ? x : 0.01f * x; }
__device__ __forceinline__ float sane(float x) { return fminf(fmaxf(x, -1e9f), 1e9f); }
__device__ __forceinline__ unsigned packbf(float a, float b) {
  union { __hip_bfloat16 h[2]; unsigned u; } cv;
  cv.h[0] = f2bf(a); cv.h[1] = f2bf(b);
  return cv.u;
}
// flagged load of a RAW INPUT element: f=1 -> f32, f=0 -> bf16
__device__ __forceinline__ float ldf(const void* p, long i, int f) {
  return f ? ((const float*)p)[i] : bf2f(((const __hip_bfloat16*)p)[i]);
}
__device__ __forceinline__ float cvt(float v) { return v; }
__device__ __forceinline__ float cvt(__hip_bfloat16 v) { return bf2f(v); }

// ---------------- dtype detector: read x as bf16; even-index elems sane => bf16 ----------------
__global__ void k_detect(const void* xp, int* flag) {
  __shared__ int cnt[NTHREADS];
  const __hip_bfloat16* h = (const __hip_bfloat16*)xp;
  int t = threadIdx.x;
  int c = 0;
  for (int j = 0; j < 8; j++) {
    float v = fabsf(bf2f(h[(t * 8 + j) * 2]));
    if (v > 1e-12f && v < 1e12f) c++;
  }
  cnt[t] = c;
  __syncthreads();
  for (int s = 128; s > 0; s >>= 1) {
    if (t < s) cnt[t] += cnt[t + s];
    __syncthreads();
  }
  if (t == 0) *flag = (cnt[0] > 1433) ? 0 : 1;   // >70% sane -> bf16 else f32
}

// ---------------- conv1 core (templated on input dtype) ----------------
template <typename T>
__device__ __forceinline__ float conv1_core(const T* __restrict__ X, const float* wl,
                                            int zo, int y, int x0) {
  float a = 0.f;
  for (int ci = 0; ci < 32; ci++) {
    const float* wp = wl + ci * 18;
#pragma unroll
    for (int kz = 0; kz < 2; kz++) {
      int z = zo - 1 + kz;
      if ((unsigned)z < 32u) {
        const T* ip = X + ((ci * 32 + z) << 12);
        const float* wq = wp + kz * 9;
#pragma unroll
        for (int ky = 0; ky < 3; ky++) {
          int yy = y - 1 + ky;
          if ((unsigned)yy < 64u) {
            const T* rp = ip + (yy << 6);
#pragma unroll
            for (int kx = 0; kx < 3; kx++) {
              int xv = x0 - 1 + kx;
              if ((unsigned)xv < 64u) a = fmaf(cvt(rp[xv]), wq[ky * 3 + kx], a);
            }
          }
        }
      }
    }
  }
  return a;
}

// conv1: (32ci,32z) -> (64co,33z), k=(2,3,3), pad 1; bf16 raw out + f32 stats
__global__ __launch_bounds__(NTHREADS) void k_conv1(const void* __restrict__ X,
                                                    const void* __restrict__ Wc,
                                                    __hip_bfloat16* __restrict__ out,
                                                    float* __restrict__ acc,
                                                    const int* __restrict__ flagp) {
  __shared__ float wl[576];
  __shared__ float red[512];
  int f = *flagp;
  int idx = blockIdx.x * NTHREADS + threadIdx.x;   // < 8,650,752
  int co  = idx / 135168;                           // co uniform per block
  int rem = idx % 135168;
  int zo  = rem >> 12;
  int y   = (rem >> 6) & 63;
  int x0  = rem & 63;
  for (int i = threadIdx.x; i < 576; i += NTHREADS) wl[i] = ldf(Wc, (long)co * 576 + i, f);
  __syncthreads();
  float a = f ? conv1_core<float>((const float*)X, wl, zo, y, x0)
              : conv1_core<__hip_bfloat16>((const __hip_bfloat16*)X, wl, zo, y, x0);
  out[idx] = f2bf(a);
  red[threadIdx.x] = a;
  red[256 + threadIdx.x] = a * a;
  __syncthreads();
  for (int s = 128; s > 0; s >>= 1) {
    if (threadIdx.x < s) {
      red[threadIdx.x] += red[threadIdx.x + s];
      red[256 + threadIdx.x] += red[256 + threadIdx.x + s];
    }
    __syncthreads();
  }
  if (threadIdx.x == 0) {
    atomicAdd(&acc[co], red[0]);
    atomicAdd(&acc[64 + co], red[256]);
  }
}

// finalize norm: acc -> scale/shift (g,b are raw inputs -> flagged)
__global__ void k_finalize(const float* __restrict__ acc, const void* __restrict__ g,
                           const void* __restrict__ b, float* __restrict__ ss, float invN,
                           const int* __restrict__ flagp) {
  int f = *flagp;
  int t = threadIdx.x;  // 64
  float mean = acc[t] * invN;
  float var  = acc[64 + t] * invN - mean * mean;
  float rstd = rsqrtf(fmaxf(var, 0.f) + 1e-5f);
  float sc   = ldf(g, t, f) * rstd;
  ss[t]      = sc;
  ss[64 + t] = ldf(b, t, f) - mean * sc;
}

// normalize conv1 raw + leaky -> bf16 h1n (all internal)
__global__ __launch_bounds__(NTHREADS) void k_normh1(const __hip_bfloat16* __restrict__ in,
                                                     const float* __restrict__ ss,
                                                     __hip_bfloat16* __restrict__ out) {
  int idx = blockIdx.x * NTHREADS + threadIdx.x;  // < 8,650,752
  int c = idx / 135168;
  float v = bf2f(in[idx]) * ss[c] + ss[64 + c];
  out[idx] = f2bf(leaky(v));
}

// conv2: (64ci,33z) -> (64co,34z); input internal bf16, weights flagged
__global__ __launch_bounds__(NTHREADS) void k_conv2(const __hip_bfloat16* __restrict__ X,
                                                    const void* __restrict__ Wc,
                                                    __hip_bfloat16* __restrict__ out,
                                                    float* __restrict__ acc,
                                                    const int* __restrict__ flagp) {
  __shared__ float wl[1152];
  __shared__ float red[512];
  int f = *flagp;
  int idx = blockIdx.x * NTHREADS + threadIdx.x;  // < 8,912,896
  int co  = idx / 139264;
  int rem = idx % 139264;
  int zo  = rem >> 12;
  int y   = (rem >> 6) & 63;
  int x0  = rem & 63;
  for (int i = threadIdx.x; i < 1152; i += NTHREADS) wl[i] = ldf(Wc, (long)co * 1152 + i, f);
  __syncthreads();
  float a = 0.f;
  for (int ci = 0; ci < 64; ci++) {
    const float* wp = wl + ci * 18;
#pragma unroll
    for (int kz = 0; kz < 2; kz++) {
      int z = zo - 1 + kz;
      if ((unsigned)z < 33u) {
        const __hip_bfloat16* ip = X + ((ci * 33 + z) << 12);
        const float* wq = wp + kz * 9;
#pragma unroll
        for (int ky = 0; ky < 3; ky++) {
          int yy = y - 1 + ky;
          if ((unsigned)yy < 64u) {
            const __hip_bfloat16* rp = ip + (yy << 6);
#pragma unroll
            for (int kx = 0; kx < 3; kx++) {
              int xv = x0 - 1 + kx;
              if ((unsigned)xv < 64u) a = fmaf(bf2f(rp[xv]), wq[ky * 3 + kx], a);
            }
          }
        }
      }
    }
  }
  out[idx] = f2bf(a);
  red[threadIdx.x] = a;
  red[256 + threadIdx.x] = a * a;
  __syncthreads();
  for (int s = 128; s > 0; s >>= 1) {
    if (threadIdx.x < s) {
      red[threadIdx.x] += red[threadIdx.x + s];
      red[256 + threadIdx.x] += red[256 + threadIdx.x + s];
    }
    __syncthreads();
  }
  if (threadIdx.x == 0) {
    atomicAdd(&acc[co], red[0]);
    atomicAdd(&acc[64 + co], red[256]);
  }
}

// normalize conv2 + leaky, slice depth to 32 -> residual h into d_out (dtype per flag)
__global__ __launch_bounds__(NTHREADS) void k_hslice(const __hip_bfloat16* __restrict__ in,
                                                     const float* __restrict__ ss,
                                                     void* __restrict__ out,
                                                     const int* __restrict__ flagp) {
  int f = *flagp;
  int idx = blockIdx.x * NTHREADS + threadIdx.x;  // < 8,388,608
  int c   = idx >> 17;
  int rem = idx & 131071;
  float v = leaky(bf2f(in[c * 139264 + rem]) * ss[c] + ss[64 + c]);
  if (f) ((float*)out)[idx] = v;
  else   ((__hip_bfloat16*)out)[idx] = f2bf(v);
}

// fused dw3x3 + pw1x1 conv -> pre2 bf16, inr stats; h read from d_out (flagged)
__global__ __launch_bounds__(NTHREADS) void k_dwpw(const void* __restrict__ h,
                                                   const void* __restrict__ dwb,
                                                   const void* __restrict__ pwb,
                                                   __hip_bfloat16* __restrict__ out,
                                                   float* __restrict__ acc,
                                                   const int* __restrict__ flagp) {
  __shared__ float tile[4096];
  __shared__ float dwl[576];
  __shared__ float pwl[4096];
  int f = *flagp;
  int t = threadIdx.x;
  for (int i = t; i < 576; i += NTHREADS) dwl[i] = ldf(dwb, i, f);
  for (int i = t; i < 4096; i += NTHREADS) pwl[i] = ldf(pwb, i, f);
  int zz = blockIdx.x >> 6, y = blockIdx.x & 63;
  __syncthreads();
  for (int i = 0; i < 16; i++) {
    int id = t + i * NTHREADS;
    int c = id >> 6, xx = id & 63;
    const float* wp = dwl + c * 9;
    long hbase = (long)c * 131072 + zz * 4096;
    float a = 0.f;
#pragma unroll
    for (int ky = 0; ky < 3; ky++) {
      int yy = y - 1 + ky;
      if ((unsigned)yy < 64u) {
#pragma unroll
        for (int kx = 0; kx < 3; kx++) {
          int xv = xx - 1 + kx;
          if ((unsigned)xv < 64u) a = fmaf(ldf(h, hbase + yy * 64 + xv, f), wp[ky * 3 + kx], a);
        }
      }
    }
    tile[id] = a;
  }
  __syncthreads();
  int obase = zz * 4096 + y * 64;
  for (int i = 0; i < 16; i++) {
    int id = t + i * NTHREADS;
    int co = id >> 6, xx = id & 63;
    const float* pp = pwl + co * 64;
    float a = 0.f;
#pragma unroll
    for (int ci = 0; ci < 64; ci++) a = fmaf(tile[ci * 64 + xx], pp[ci], a);
    out[co * 131072 + obase + xx] = f2bf(a);
    float sv = a, sq = a * a;
#pragma unroll
    for (int m = 32; m > 0; m >>= 1) {
      sv += __shfl_xor(sv, m, 64);
      sq += __shfl_xor(sq, m, 64);
    }
    if ((t & 63) == 0) {   // co uniform per wave
      atomicAdd(&acc[co], sv);
      atomicAdd(&acc[64 + co], sq);
    }
  }
}

// x2 = h + silu(norm(pre2)); LayerNorm over C=64 -> bf16 seq
__global__ __launch_bounds__(NTHREADS) void k_x2ln(const void* __restrict__ h,
                                                   const __hip_bfloat16* __restrict__ p2,
                                                   const float* __restrict__ ssr,
                                                   const void* __restrict__ lng,
                                                   const void* __restrict__ lnb,
                                                   __hip_bfloat16* __restrict__ out,
                                                   const int* __restrict__ flagp) {
  __shared__ float sc[64], sh[64], sg[64], sb[64];
  int f = *flagp;
  int t = threadIdx.x;
  if (t < 64) {
    sc[t] = ssr[t];
    sh[t] = ssr[64 + t];
    sg[t] = ldf(lng, t, f);
    sb[t] = ldf(lnb, t, f);
  }
  __syncthreads();
  int r = blockIdx.x * NTHREADS + t;  // 0..131071
  float v[64];
  float s1 = 0.f;
#pragma unroll
  for (int c = 0; c < 64; c++) {
    float hv = ldf(h, (long)c * 131072 + r, f);
    float pv = bf2f(p2[c * 131072 + r]);
    pv = sc[c] * pv + sh[c];
    float x2 = hv + pv * sigm(pv);
    v[c] = x2;
    s1 += x2;
  }
  float m = s1 * (1.f / 64.f);
  float s2 = 0.f;
#pragma unroll
  for (int c = 0; c < 64; c++) {
    float d = v[c] - m;
    s2 += d * d;
  }
  float rstd = rsqrtf(s2 * (1.f / 64.f) + 1e-5f);
  uint4* o4 = (uint4*)(out + (size_t)r * 64);
#pragma unroll
  for (int q = 0; q < 8; q++) {
    int c = q * 8;
    uint4 o;
    o.x = packbf((v[c + 0] - m) * rstd * sg[c + 0] + sb[c + 0],
                 (v[c + 1] - m) * rstd * sg[c + 1] + sb[c + 1]);
    o.y = packbf((v[c + 2] - m) * rstd * sg[c + 2] + sb[c + 2],
                 (v[c + 3] - m) * rstd * sg[c + 3] + sb[c + 3]);
    o.z = packbf((v[c + 4] - m) * rstd * sg[c + 4] + sb[c + 4],
                 (v[c + 5] - m) * rstd * sg[c + 5] + sb[c + 5]);
    o.w = packbf((v[c + 6] - m) * rstd * sg[c + 6] + sb[c + 6],
                 (v[c + 7] - m) * rstd * sg[c + 7] + sb[c + 7]);
    o4[q] = o;
  }
}

// in_proj chunk: seq (global rows, bf16) -> x_in_q, zg_q (chunk-local bf16)
__global__ __launch_bounds__(NTHREADS, 2) void k_inproj(const __hip_bfloat16* __restrict__ seq,
                                                        const void* __restrict__ Wb,
                                                        __hip_bfloat16* __restrict__ x_in,
                                                        __hip_bfloat16* __restrict__ zg,
                                                        int nbase,
                                                        const int* __restrict__ flagp) {
  int f = *flagp;
  int t = threadIdx.x;  // output column j (0..255)
  float w[64];
#pragma unroll
  for (int k = 0; k < 64; k++) w[k] = ldf(Wb, (long)t * 64 + k, f);
  long rq0 = (long)blockIdx.x * 16;               // chunk-local first row
  int z = (int)(rq0 >> 10), nl0 = (int)(rq0 & 1023);
  long g0 = ((long)z << 12) + nbase + nl0;        // global first row (16 consecutive)
  float acc[16];
#pragma unroll
  for (int r = 0; r < 16; r++) acc[r] = 0.f;
#pragma unroll
  for (int r = 0; r < 16; r++) {
    const uint4* ar = reinterpret_cast<const uint4*>(seq + (size_t)(g0 + r) * 64);
#pragma unroll
    for (int q = 0; q < 8; q++) {
      uint4 u = ar[q];
      float a = acc[r];
      a = fmaf(b2f_lo(u.x), w[q * 8 + 0], a);
      a = fmaf(b2f_hi(u.x), w[q * 8 + 1], a);
      a = fmaf(b2f_lo(u.y), w[q * 8 + 2], a);
      a = fmaf(b2f_hi(u.y), w[q * 8 + 3], a);
      a = fmaf(b2f_lo(u.z), w[q * 8 + 4], a);
      a = fmaf(b2f_hi(u.z), w[q * 8 + 5], a);
      a = fmaf(b2f_lo(u.w), w[q * 8 + 6], a);
      a = fmaf(b2f_hi(u.w), w[q * 8 + 7], a);
      acc[r] = a;
    }
  }
  if (t < 128) {
    __hip_bfloat16* ob = x_in + rq0 * 128 + t;
#pragma unroll
    for (int r = 0; r < 16; r++) ob[r * 128] = f2bf(acc[r]);
  } else {
    __hip_bfloat16* ob = zg + rq0 * 128 + (t - 128);
#pragma unroll
    for (int r = 0; r < 16; r++) ob[r * 128] = f2bf(acc[r]);
  }
}

// causal depthwise conv1d k=4 over z + bias + silu, IN PLACE on x_in chunk
__global__ __launch_bounds__(NTHREADS) void k_conv1d_ip(__hip_bfloat16* xio,
                                                        const void* __restrict__ wb,
                                                        const void* __restrict__ bb,
                                                        const int* __restrict__ flagp) {
  int f = *flagp;
  int gid = blockIdx.x * NTHREADS + threadIdx.x;  // < 131,072
  int d = gid & 127, nl = gid >> 7;
  float w0 = ldf(wb, d * 4 + 0, f), w1 = ldf(wb, d * 4 + 1, f);
  float w2 = ldf(wb, d * 4 + 2, f), w3 = ldf(wb, d * 4 + 3, f);
  float bias = ldf(bb, d, f);
  float h0 = 0.f, h1 = 0.f, h2 = 0.f;
  size_t off = (size_t)nl * 128 + d;
  const size_t stride = 1024u * 128u;
  for (int z = 0; z < 32; z++) {
    float xv = bf2f(xio[off]);
    float a = bias;
    a = fmaf(h0, w0, a);
    a = fmaf(h1, w1, a);
    a = fmaf(h2, w2, a);
    a = fmaf(xv, w3, a);
    xio[off] = f2bf(a * sigm(a));
    h0 = h1; h1 = h2; h2 = xv;
    off += stride;
  }
}

// x_proj chunk: (32768,128)bf16 x (36,128)^T -> xdbl_q (32768,36) bf16
__global__ __launch_bounds__(NTHREADS) void k_xproj(const __hip_bfloat16* __restrict__ A,
                                                    const void* __restrict__ Wb,
                                                    __hip_bfloat16* __restrict__ out,
                                                    const int* __restrict__ flagp) {
  __shared__ float Wt[128 * 41];
  int f = *flagp;
  int t = threadIdx.x;
  for (int i = t; i < 36 * 128; i += NTHREADS) {
    int j = i >> 7, k = i & 127;
    Wt[k * 41 + j] = ldf(Wb, i, f);
  }
  __syncthreads();
  int lane = t & 63, wv = t >> 6;
  int jc = lane < 36 ? lane : 0;
  long m0 = (long)blockIdx.x * 32 + wv * 8;       // chunk-local rows
  float acc[8];
#pragma unroll
  for (int r = 0; r < 8; r++) acc[r] = 0.f;
#pragma unroll
  for (int q = 0; q < 16; q++) {
    float w0 = Wt[(q * 8 + 0) * 41 + jc];
    float w1 = Wt[(q * 8 + 1) * 41 + jc];
    float w2 = Wt[(q * 8 + 2) * 41 + jc];
    float w3 = Wt[(q * 8 + 3) * 41 + jc];
    float w4 = Wt[(q * 8 + 4) * 41 + jc];
    float w5 = Wt[(q * 8 + 5) * 41 + jc];
    float w6 = Wt[(q * 8 + 6) * 41 + jc];
    float w7 = Wt[(q * 8 + 7) * 41 + jc];
#pragma unroll
    for (int r = 0; r < 8; r++) {
      uint4 u = *reinterpret_cast<const uint4*>(A + (size_t)(m0 + r) * 128 + q * 8);
      float a = acc[r];
      a = fmaf(b2f_lo(u.x), w0, a);
      a = fmaf(b2f_hi(u.x), w1, a);
      a = fmaf(b2f_lo(u.y), w2, a);
      a = fmaf(b2f_hi(u.y), w3, a);
      a = fmaf(b2f_lo(u.z), w4, a);
      a = fmaf(b2f_hi(u.z), w5, a);
      a = fmaf(b2f_lo(u.w), w6, a);
      a = fmaf(b2f_hi(u.w), w7, a);
      acc[r] = a;
    }
  }
  if (lane < 36) {
#pragma unroll
    for (int r = 0; r < 8; r++) out[(size_t)(m0 + r) * 36 + lane] = f2bf(acc[r]);
  }
}

// selective scan chunk: dt inline, D skip, silu(z) gate; y overwrites x_in_q
__global__ __launch_bounds__(NTHREADS) void k_scan(const __hip_bfloat16* __restrict__ xdbl,
                                                   __hip_bfloat16* uy,
                                                   const __hip_bfloat16* __restrict__ zg,
                                                   const void* __restrict__ dtw,
                                                   const void* __restrict__ dtb,
                                                   const void* __restrict__ Alog,
                                                   const void* __restrict__ Dp,
                                                   const int* __restrict__ flagp) {
  int f = *flagp;
  int gid = blockIdx.x * NTHREADS + threadIdx.x;  // < 131,072
  int d = gid & 127, nl = gid >> 7;
  float A[16];
#pragma unroll
  for (int s = 0; s < 16; s++) A[s] = -__expf(fminf(ldf(Alog, d * 16 + s, f), 60.f));
  float W0 = ldf(dtw, d * 4 + 0, f), W1 = ldf(dtw, d * 4 + 1, f);
  float W2 = ldf(dtw, d * 4 + 2, f), W3 = ldf(dtw, d * 4 + 3, f);
  float bias = ldf(dtb, d, f);
  float Dv = ldf(Dp, d, f);
  float st[16];
#pragma unroll
  for (int s = 0; s < 16; s++) st[s] = 0.f;
  for (int z = 0; z < 32; z++) {
    size_t r = (size_t)(z << 10) | nl;            // chunk-local row
    const __hip_bfloat16* bp = xdbl + r * 36;
    float v = bias;
    v = fmaf(bf2f(bp[0]), W0, v);
    v = fmaf(bf2f(bp[1]), W1, v);
    v = fmaf(bf2f(bp[2]), W2, v);
    v = fmaf(bf2f(bp[3]), W3, v);
    float dtv = v > 20.f ? v : log1pf(__expf(v));
    dtv = fminf(fmaxf(dtv, 0.f), 60.f);
    float u = sane(bf2f(uy[r * 128 + d]));
    float zv = sane(bf2f(zg[r * 128 + d]));
    float du = dtv * u;
    float y = 0.f;
#pragma unroll
    for (int s = 0; s < 16; s++) {
      float Bv = bf2f(bp[4 + s]);
      float Cv = bf2f(bp[20 + s]);
      st[s] = fmaf(__expf(dtv * A[s]), st[s], du * Bv);
      y = fmaf(st[s], Cv, y);
    }
    y = sane((y + Dv * u) * (zv * sigm(zv)));
    uy[r * 128 + d] = f2bf(y);
  }
}

// W_comb = proj_w @ out_proj_w  (64,128), f32
__global__ void k_wcomb(const void* __restrict__ pw, const void* __restrict__ opw,
                        float* __restrict__ wc, const int* __restrict__ flagp) {
  int f = *flagp;
  int gid = blockIdx.x * NTHREADS + threadIdx.x;  // 8192
  int d = gid & 127, o = gid >> 7;
  float a = 0.f;
#pragma unroll
  for (int j = 0; j < 64; j++) a = fmaf(ldf(pw, o * 64 + j, f), ldf(opw, j * 128 + d, f), a);
  wc[gid] = a;
}

// out_proj+proj chunk -> s2 (global rows, bf16)
__global__ __launch_bounds__(NTHREADS) void k_outproj(const __hip_bfloat16* __restrict__ A,
                                                      const float* __restrict__ Wc,
                                                      const void* __restrict__ bias,
                                                      __hip_bfloat16* __restrict__ out,
                                                      int nbase,
                                                      const int* __restrict__ flagp) {
  __shared__ float Wt[128 * 65];
  int f = *flagp;
  int t = threadIdx.x;
  for (int i = t; i < 8192; i += NTHREADS) {
    int o = i >> 7, k = i & 127;
    Wt[k * 65 + o] = Wc[i];
  }
  __syncthreads();
  int o = t & 63, wv = t >> 6;
  long m0 = (long)blockIdx.x * 32 + wv * 8;       // chunk-local rows
  float acc[8];
#pragma unroll
  for (int r = 0; r < 8; r++) acc[r] = 0.f;
#pragma unroll
  for (int q = 0; q < 16; q++) {
    float w0 = Wt[(q * 8 + 0) * 65 + o];
    float w1 = Wt[(q * 8 + 1) * 65 + o];
    float w2 = Wt[(q * 8 + 2) * 65 + o];
    float w3 = Wt[(q * 8 + 3) * 65 + o];
    float w4 = Wt[(q * 8 + 4) * 65 + o];
    float w5 = Wt[(q * 8 + 5) * 65 + o];
    float w6 = Wt[(q * 8 + 6) * 65 + o];
    float w7 = Wt[(q * 8 + 7) * 65 + o];
#pragma unroll
    for (int r = 0; r < 8; r++) {
      uint4 u = *reinterpret_cast<const uint4*>(A + (size_t)(m0 + r) * 128 + q * 8);
      float a = acc[r];
      a = fmaf(b2f_lo(u.x), w0, a);
      a = fmaf(b2f_hi(u.x), w1, a);
      a = fmaf(b2f_lo(u.y), w2, a);
      a = fmaf(b2f_hi(u.y), w3, a);
      a = fmaf(b2f_lo(u.z), w4, a);
      a = fmaf(b2f_hi(u.z), w5, a);
      a = fmaf(b2f_lo(u.w), w6, a);
      a = fmaf(b2f_hi(u.w), w7, a);
      acc[r] = a;
    }
  }
  float b = ldf(bias, o, f);
  int z = (int)(m0 >> 10), nl0 = (int)(m0 & 1023);
  long g0 = ((long)z << 12) + nbase + nl0;
#pragma unroll
  for (int r = 0; r < 8; r++) out[(size_t)(g0 + r) * 64 + o] = f2bf(sane(acc[r] + b));
}

// per-channel stats over s2[r*64+c] (bf16)
__global__ __launch_bounds__(NTHREADS) void k_pnstats2(const __hip_bfloat16* __restrict__ s2,
                                                       float* __restrict__ acc) {
  __shared__ float rs[64], rq[64];
  int t = threadIdx.x;
  int c = t & 63;
  int sub = t >> 6;
  float s = 0.f, q = 0.f;
  size_t r0 = (size_t)blockIdx.x * 2048 + sub;
  for (int i = 0; i < 512; i++) {
    float v = sane(bf2f(s2[(r0 + (size_t)i * 4) * 64 + c]));
    s += v;
    q += v * v;
  }
  if (sub == 0) { rs[c] = 0.f; rq[c] = 0.f; }
  __syncthreads();
  for (int w = 0; w < 4; w++) {
    if (sub == w) { rs[c] += s; rq[c] += q; }
    __syncthreads();
  }
  if (t < 64) {
    atomicAdd(&acc[t], rs[t]);
    atomicAdd(&acc[64 + t], rq[t]);
  }
}

// final: norm s2, transpose (r,c)->(c,z,n), add residual (in d_out), write d_out (dtype per flag)
__global__ __launch_bounds__(NTHREADS) void k_final(const __hip_bfloat16* __restrict__ s2,
                                                    void* __restrict__ io,   // residual in, out
                                                    const float* __restrict__ ss,
                                                    const int* __restrict__ flagp) {
  __shared__ float tile[64 * 65];
  __shared__ float sc[64], sh[64];
  int f = *flagp;
  int t = threadIdx.x;
  if (t < 64) {
    sc[t] = ss[t];
    sh[t] = ss[64 + t];
  }
  int z = blockIdx.x >> 6, n0 = (blockIdx.x & 63) << 6;
  size_t base = ((size_t)z * 4096 + n0) * 64;
  __syncthreads();
#pragma unroll
  for (int jj = 0; jj < 16; jj++) {
    int id = t + jj * NTHREADS;
    int i = id >> 6, c = id & 63;
    float v = sane(bf2f(s2[base + id]));
    tile[i * 65 + c] = sc[c] * v + sh[c];
  }
  __syncthreads();
#pragma unroll
  for (int jj = 0; jj < 16; jj++) {
    int id = t + jj * NTHREADS;
    int c = id >> 6, nl = id & 63;
    size_t off = (size_t)c * 131072 + (size_t)z * 4096 + n0 + nl;
    if (f) {
      float* o = (float*)io;
      o[off] = sane(o[off] + tile[nl * 65 + c]);      // read residual then overwrite
    } else {
      __hip_bfloat16* o = (__hip_bfloat16*)io;
      o[off] = f2bf(sane(bf2f(o[off]) + tile[nl * 65 + c]));
    }
  }
}

// ---------------- launch ----------------
extern "C" void kernel_launch(void* const* d_in, const int* in_sizes, int n_in,
                              void* d_out, int out_size, void* d_ws, size_t ws_size,
                              hipStream_t stream) {
  (void)in_sizes; (void)n_in; (void)out_size; (void)ws_size;
  const void* x        = d_in[0];
  const void* c1_w     = d_in[1];
  const void* in1_g    = d_in[2];
  const void* in1_b    = d_in[3];
  const void* c2_w     = d_in[4];
  const void* in2_g    = d_in[5];
  const void* in2_b    = d_in[6];
  const void* dw_w     = d_in[7];
  const void* pw_w     = d_in[8];
  const void* inr_g    = d_in[9];
  const void* inr_b    = d_in[10];
  const void* ln_g     = d_in[11];
  const void* ln_b     = d_in[12];
  const void* in_proj_w= d_in[13];
  const void* conv1d_w = d_in[14];
  const void* conv1d_b = d_in[15];
  const void* x_proj_w = d_in[16];
  const void* dt_proj_w= d_in[17];
  const void* dt_proj_b= d_in[18];
  const void* A_log    = d_in[19];
  const void* D_p      = d_in[20];
  const void* out_proj_w=d_in[21];
  const void* proj_w   = d_in[22];
  const void* proj_b   = d_in[23];
  const void* pn_g     = d_in[24];
  const void* pn_b     = d_in[25];

  char* wb = (char*)d_ws;
  // Byte layout, TOTAL = 38,310,912 B = 36.54 MiB.
  // R0 [0, 17,825,792): c1raw(17.3MB) -> c2raw(17.8MB) -> seq==s2(16.7MB, chunk-disjoint rows)
  __hip_bfloat16* c1raw = (__hip_bfloat16*)wb;
  __hip_bfloat16* c2raw = (__hip_bfloat16*)wb;
  __hip_bfloat16* seq   = (__hip_bfloat16*)wb;
  __hip_bfloat16* s2    = (__hip_bfloat16*)wb;
  // R1 [17,825,792, 35,651,584): h1n(17.3MB) -> pre2(16.7MB) -> x_in_q(8.4MB)|zg_q(8.4MB)
  __hip_bfloat16* h1n   = (__hip_bfloat16*)(wb + 17825792);
  __hip_bfloat16* pre2  = (__hip_bfloat16*)(wb + 17825792);
  __hip_bfloat16* x_in  = (__hip_bfloat16*)(wb + 17825792);
  __hip_bfloat16* zgb   = (__hip_bfloat16*)(wb + 17825792 + 8388608);
  // R2 [35,651,584, 38,272,  ...): xdbl chunk 2,359,296 B
  __hip_bfloat16* xdbl  = (__hip_bfloat16*)(wb + 35651584);
  // stats [38,010,880 .. +~37KB)
  float*          fst   = (float*)(wb + 38010880);
  // residual hres lives in d_out (dtype per flag); k_final reads-then-writes same offsets.

  float* acc_in1 = fst;
  float* acc_in2 = fst + 128;
  float* acc_inr = fst + 256;
  float* acc_pn  = fst + 384;
  float* ss_in1  = fst + 512;
  float* ss_in2  = fst + 640;
  float* ss_inr  = fst + 768;
  float* ss_pn   = fst + 896;
  float* wcomb   = fst + 1024;          // 8192 f
  int*   flagp   = (int*)(fst + 9216);  // detector output

  hipMemsetAsync(fst, 0, 512 * sizeof(float), stream);

  k_detect<<<1, NTHREADS, 0, stream>>>(x, flagp);
  k_conv1<<<33792, NTHREADS, 0, stream>>>(x, c1_w, c1raw, acc_in1, flagp);
  k_finalize<<<1, 64, 0, stream>>>(acc_in1, in1_g, in1_b, ss_in1, 1.0f / 135168.0f, flagp);
  k_normh1<<<33792, NTHREADS, 0, stream>>>(c1raw, ss_in1, h1n);
  k_conv2<<<34816, NTHREADS, 0, stream>>>(h1n, c2_w, c2raw, acc_in2, flagp);
  k_finalize<<<1, 64, 0, stream>>>(acc_in2, in2_g, in2_b, ss_in2, 1.0f / 139264.0f, flagp);
  k_hslice<<<32768, NTHREADS, 0, stream>>>(c2raw, ss_in2, d_out, flagp);
  k_dwpw<<<2048, NTHREADS, 0, stream>>>(d_out, dw_w, pw_w, pre2, acc_inr, flagp);
  k_finalize<<<1, 64, 0, stream>>>(acc_inr, inr_g, inr_b, ss_inr, 1.0f / 131072.0f, flagp);
  k_x2ln<<<512, NTHREADS, 0, stream>>>(d_out, pre2, ss_inr, ln_g, ln_b, seq, flagp);
  k_wcomb<<<32, NTHREADS, 0, stream>>>(proj_w, out_proj_w, wcomb, flagp);
  for (int q = 0; q < 4; q++) {
    int nbase = q * 1024;
    k_inproj<<<2048, NTHREADS, 0, stream>>>(seq, in_proj_w, x_in, zgb, nbase, flagp);
    k_conv1d_ip<<<512, NTHREADS, 0, stream>>>(x_in, conv1d_w, conv1d_b, flagp);
    k_xproj<<<1024, NTHREADS, 0, stream>>>(x_in, x_proj_w, xdbl, flagp);
    k_scan<<<512, NTHREADS, 0, stream>>>(xdbl, x_in, zgb, dt_proj_w, dt_proj_b, A_log, D_p, flagp);
    k_outproj<<<1024, NTHREADS, 0, stream>>>(x_in, wcomb, proj_b, s2, nbase, flagp);
  }
  k_pnstats2<<<64, NTHREADS, 0, stream>>>(s2, acc_pn);
  k_finalize<<<1, 64, 0, stream>>>(acc_pn, pn_g, pn_b, ss_pn, 1.0f / 131072.0f, flagp);
  k_final<<<2048, NTHREADS, 0, stream>>>(s2, d_out, ss_pn, flagp);
}

// Round 7
// 1941.324 us; speedup vs baseline: 3.2063x; 3.2063x over previous
//
#include <hip/hip_runtime.h>
#include <hip/hip_bf16.h>

// Hybrid decoder block, MFMA implicit-GEMM convs, channels-last internals.
// row convention: r = z*4096 + n, n = y*64+x. Mamba section chunked 4x over n.
#define NTHREADS 256

typedef __attribute__((ext_vector_type(8))) short bs8_t;   // 8 bf16 (4 VGPRs)
typedef __attribute__((ext_vector_type(4))) float f4_t;    // 4 fp32 acc

__device__ __forceinline__ float bf2f(__hip_bfloat16 v) { return __bfloat162float(v); }
__device__ __forceinline__ __hip_bfloat16 f2bf(float v) { return __float2bfloat16(v); }
__device__ __forceinline__ float b2f_lo(unsigned int p) { return __uint_as_float(p << 16); }
__device__ __forceinline__ float b2f_hi(unsigned int p) { return __uint_as_float(p & 0xffff0000u); }
__device__ __forceinline__ float sigm(float x) { return 1.f / (1.f + __expf(-x)); }
__device__ __forceinline__ float leaky(float x) { return x > 0.f ? x : 0.01f * x; }
__device__ __forceinline__ float sane(float x) { return fminf(fmaxf(x, -1e9f), 1e9f); }
__device__ __forceinline__ unsigned packbf(float a, float b) {
  union { __hip_bfloat16 h[2]; unsigned u; } cv;
  cv.h[0] = f2bf(a); cv.h[1] = f2bf(b);
  return cv.u;
}
// flagged load of a RAW INPUT element: f=1 -> f32, f=0 -> bf16
__device__ __forceinline__ float ldf(const void* p, long i, int f) {
  return f ? ((const float*)p)[i] : bf2f(((const __hip_bfloat16*)p)[i]);
}

// ---------------- dtype detector ----------------
__global__ void k_detect(const void* xp, int* flag) {
  __shared__ int cnt[NTHREADS];
  const __hip_bfloat16* h = (const __hip_bfloat16*)xp;
  int t = threadIdx.x;
  int c = 0;
  for (int j = 0; j < 8; j++) {
    float v = fabsf(bf2f(h[(t * 8 + j) * 2]));
    if (v > 1e-12f && v < 1e12f) c++;
  }
  cnt[t] = c;
  __syncthreads();
  for (int s = 128; s > 0; s >>= 1) {
    if (t < s) cnt[t] += cnt[t + s];
    __syncthreads();
  }
  if (t == 0) *flag = (cnt[0] > 1433) ? 0 : 1;
}

// ---------------- pad1: x (ci-first) -> P1[z'(34)][y'(66)][x'(66)][32] bf16, zero pads ----------------
__global__ __launch_bounds__(NTHREADS) void k_pad1(const void* __restrict__ x,
                                                   __hip_bfloat16* __restrict__ P1,
                                                   const int* __restrict__ flagp) {
  __shared__ float tile[64 * 33];
  int f = *flagp;
  int zp = blockIdx.x / 66, yp = blockIdx.x % 66;
  long rowbase = ((long)zp * 66 + yp) * 66 * 32;
  int t = threadIdx.x;
  if (zp == 0 || zp == 33 || yp == 0 || yp == 65) {
    for (int i = t; i < 2112; i += NTHREADS) P1[rowbase + i] = f2bf(0.f);
    return;
  }
  int z = zp - 1, y = yp - 1;
#pragma unroll
  for (int j = 0; j < 8; j++) {
    int idx = t + j * NTHREADS;        // < 2048
    int ci = idx >> 6, xx = idx & 63;
    tile[xx * 33 + ci] = ldf(x, (long)(ci * 32 + z) * 4096 + y * 64 + xx, f);
  }
  __syncthreads();
#pragma unroll
  for (int j = 0; j < 8; j++) {
    int idx = t + j * NTHREADS;
    int xx = idx >> 5, ci = idx & 31;
    P1[rowbase + (xx + 1) * 32 + ci] = f2bf(tile[xx * 33 + ci]);
  }
  if (t < 32) P1[rowbase + t] = f2bf(0.f);                 // x'=0 pad
  else if (t < 64) P1[rowbase + 65 * 32 + (t - 32)] = f2bf(0.f);  // x'=65 pad
}

// ---------------- weight reorg: cw (co,ci,2,3,3) -> W[s][co][ci] bf16 ----------------
__global__ void k_prepw(const void* __restrict__ cw, __hip_bfloat16* __restrict__ W,
                        int CI, const int* __restrict__ flagp) {
  int f = *flagp;
  int gid = blockIdx.x * NTHREADS + threadIdx.x;   // < 18*64*CI
  int s = gid / (64 * CI);
  int rem = gid % (64 * CI);
  int co = rem / CI, ci = rem % CI;
  W[gid] = f2bf(ldf(cw, (long)(co * CI + ci) * 18 + s, f));
  (void)s;
}

// ---------------- MFMA implicit-GEMM conv: P (padded, ci-last) x W[s][co][ci] -> out[zo][y][x][co] ----------------
// grid = ZOUT*16 blocks; block = 4 waves; wave w handles y = (blk%16)*4 + w, 64 x, 64 co.
template <int CI, int CIP>
__global__ __launch_bounds__(NTHREADS) void k_gemm_conv(const __hip_bfloat16* __restrict__ Pb,
                                                        const __hip_bfloat16* __restrict__ Wb,
                                                        __hip_bfloat16* __restrict__ out) {
  __shared__ unsigned short Wl[3 * 64 * CIP];
  const unsigned short* P = (const unsigned short*)Pb;
  const unsigned short* W = (const unsigned short*)Wb;
  int t = threadIdx.x;
  int wv = t >> 6, lane = t & 63;
  int m = lane & 15, quad = lane >> 4;
  int zo = blockIdx.x >> 4;
  int y  = ((blockIdx.x & 15) << 2) + wv;
  f4_t zero4 = {0.f, 0.f, 0.f, 0.f};
  f4_t acc[4][4];
#pragma unroll
  for (int mt = 0; mt < 4; mt++)
#pragma unroll
    for (int nt = 0; nt < 4; nt++) acc[mt][nt] = zero4;

  for (int kz = 0; kz < 2; kz++) {
    for (int ky = 0; ky < 3; ky++) {
      __syncthreads();
      int s0 = (kz * 3 + ky) * 3;
      const unsigned short* wsrc = W + (long)s0 * 64 * CI;
      for (int i = t; i < 3 * 64 * CI; i += NTHREADS) {
        int kx = i / (64 * CI), rem = i % (64 * CI);
        int co = rem / CI, ci = rem % CI;
        Wl[(kx * 64 + co) * CIP + ci] = wsrc[i];
      }
      __syncthreads();
      int pz = zo + kz, py = y + ky;
      const unsigned short* prow = P + ((long)(pz * 66 + py) * 66) * CI;
#pragma unroll
      for (int kx = 0; kx < 3; kx++) {
#pragma unroll
        for (int ch = 0; ch < CI / 32; ch++) {
          int kof = kx * CI + ch * 32 + quad * 8;
          bs8_t a0 = *(const bs8_t*)(prow + (0 * 16 + m) * CI + kof);
          bs8_t a1 = *(const bs8_t*)(prow + (1 * 16 + m) * CI + kof);
          bs8_t a2 = *(const bs8_t*)(prow + (2 * 16 + m) * CI + kof);
          bs8_t a3 = *(const bs8_t*)(prow + (3 * 16 + m) * CI + kof);
#pragma unroll
          for (int nt = 0; nt < 4; nt++) {
            bs8_t b = *(const bs8_t*)&Wl[(kx * 64 + nt * 16 + m) * CIP + ch * 32 + quad * 8];
            acc[0][nt] = __builtin_amdgcn_mfma_f32_16x16x32_bf16(a0, b, acc[0][nt], 0, 0, 0);
            acc[1][nt] = __builtin_amdgcn_mfma_f32_16x16x32_bf16(a1, b, acc[1][nt], 0, 0, 0);
            acc[2][nt] = __builtin_amdgcn_mfma_f32_16x16x32_bf16(a2, b, acc[2][nt], 0, 0, 0);
            acc[3][nt] = __builtin_amdgcn_mfma_f32_16x16x32_bf16(a3, b, acc[3][nt], 0, 0, 0);
          }
        }
      }
    }
  }
  long obase = ((long)(zo * 64 + y) * 64) * 64;
#pragma unroll
  for (int mt = 0; mt < 4; mt++)
#pragma unroll
    for (int nt = 0; nt < 4; nt++) {
      int co = nt * 16 + m;
#pragma unroll
      for (int rg = 0; rg < 4; rg++) {
        int xx = mt * 16 + quad * 4 + rg;
        out[obase + xx * 64 + co] = f2bf(acc[mt][nt][rg]);
      }
    }
}

// ---------------- per-channel stats over channels-last [rows][64] bf16; grid 256 ----------------
__global__ __launch_bounds__(NTHREADS) void k_stats_cl(const __hip_bfloat16* __restrict__ in,
                                                       float* __restrict__ acc, int rpb) {
  __shared__ float rs[64], rq[64];
  int t = threadIdx.x;
  int c = t & 63, sub = t >> 6;
  float s = 0.f, q = 0.f;
  long r0 = (long)blockIdx.x * rpb + sub;
  for (int i = 0; i < rpb / 4; i++) {
    float v = bf2f(in[(r0 + (long)i * 4) * 64 + c]);
    s += v;
    q += v * v;
  }
  if (sub == 0) { rs[c] = 0.f; rq[c] = 0.f; }
  __syncthreads();
  for (int w = 0; w < 4; w++) {
    if (sub == w) { rs[c] += s; rq[c] += q; }
    __syncthreads();
  }
  if (t < 64) {
    atomicAdd(&acc[t], rs[t]);
    atomicAdd(&acc[64 + t], rq[t]);
  }
}

// finalize norm: acc -> scale/shift
__global__ void k_finalize(const float* __restrict__ acc, const void* __restrict__ g,
                           const void* __restrict__ b, float* __restrict__ ss, float invN,
                           const int* __restrict__ flagp) {
  int f = *flagp;
  int t = threadIdx.x;  // 64
  float mean = acc[t] * invN;
  float var  = acc[64 + t] * invN - mean * mean;
  float rstd = rsqrtf(fmaxf(var, 0.f) + 1e-5f);
  float sc   = ldf(g, t, f) * rstd;
  ss[t]      = sc;
  ss[64 + t] = ldf(b, t, f) - mean * sc;
}

// ---------------- normpad: c1raw [z33][y][x][64] -> norm+leaky -> P2[z'(35)][66][66][64], zero pads ----------------
__global__ __launch_bounds__(NTHREADS) void k_normpad(const __hip_bfloat16* __restrict__ in,
                                                      const float* __restrict__ ss,
                                                      __hip_bfloat16* __restrict__ P2) {
  int zp = blockIdx.x / 66, yp = blockIdx.x % 66;
  long rowbase = ((long)zp * 66 + yp) * 66 * 64;
  int t = threadIdx.x;
  if (zp == 0 || zp == 34 || yp == 0 || yp == 65) {
    for (int i = t; i < 4224; i += NTHREADS) P2[rowbase + i] = f2bf(0.f);
    return;
  }
  int z = zp - 1, y = yp - 1;
#pragma unroll
  for (int j = 0; j < 16; j++) {
    int idx = t + j * NTHREADS;        // < 4096
    int xx = idx >> 6, co = idx & 63;
    float v = bf2f(in[((long)(z * 64 + y) * 64 + xx) * 64 + co]) * ss[co] + ss[64 + co];
    P2[rowbase + (xx + 1) * 64 + co] = f2bf(leaky(v));
  }
  if (t < 64) P2[rowbase + t] = f2bf(0.f);
  else if (t < 128) P2[rowbase + 65 * 64 + (t - 64)] = f2bf(0.f);
}

// ---------------- hslice: c2raw[r<131072][c] -> norm+leaky -> h_cl[r][c] bf16 + residual d_out[c][r] ----------------
__global__ __launch_bounds__(NTHREADS) void k_hslice_cl(const __hip_bfloat16* __restrict__ in,
                                                        const float* __restrict__ ss,
                                                        __hip_bfloat16* __restrict__ hcl,
                                                        void* __restrict__ resid,
                                                        const int* __restrict__ flagp) {
  __shared__ float tile[64 * 65];
  int f = *flagp;
  int z = blockIdx.x >> 6, y = blockIdx.x & 63;
  long r0 = (long)z * 4096 + y * 64;
  int t = threadIdx.x;
#pragma unroll
  for (int j = 0; j < 16; j++) {
    int idx = t + j * NTHREADS;        // < 4096
    int xx = idx >> 6, co = idx & 63;
    float v = leaky(bf2f(in[(r0 + xx) * 64 + co]) * ss[co] + ss[64 + co]);
    hcl[(r0 + xx) * 64 + co] = f2bf(v);
    tile[xx * 65 + co] = v;
  }
  __syncthreads();
#pragma unroll
  for (int j = 0; j < 16; j++) {
    int idx = t + j * NTHREADS;
    int co = idx >> 6, xx = idx & 63;
    long off = (long)co * 131072 + r0 + xx;
    if (f) ((float*)resid)[off] = tile[xx * 65 + co];
    else   ((__hip_bfloat16*)resid)[off] = f2bf(tile[xx * 65 + co]);
  }
}

// ---------------- fused dw3x3+pw1x1, channels-last, inr stats ----------------
__global__ __launch_bounds__(NTHREADS) void k_dwpw_cl(const __hip_bfloat16* __restrict__ hcl,
                                                      const void* __restrict__ dwb,
                                                      const void* __restrict__ pwb,
                                                      __hip_bfloat16* __restrict__ out,
                                                      float* __restrict__ acc,
                                                      const int* __restrict__ flagp) {
  __shared__ unsigned short hl[3 * 64 * 64];
  __shared__ float dwt[64 * 64];
  __shared__ float pwl[64 * 64];
  __shared__ float dwl[576];
  __shared__ float red[256];
  int f = *flagp;
  int t = threadIdx.x;
  int z = blockIdx.x >> 6, y = blockIdx.x & 63;
  for (int i = t; i < 576; i += NTHREADS) dwl[i] = ldf(dwb, i, f);
  for (int i = t; i < 4096; i += NTHREADS) {
    int ci = i >> 6, co = i & 63;
    pwl[ci * 64 + co] = ldf(pwb, (long)co * 64 + ci, f);
  }
  const unsigned short* hsrc = (const unsigned short*)hcl;
  for (int i = t; i < 12288; i += NTHREADS) {
    int dy = i / 4096, rem = i & 4095;
    int ry = y - 1 + dy;
    hl[i] = ((unsigned)ry < 64u) ? hsrc[((long)z * 4096 + ry * 64) * 64 + rem] : 0;
  }
  __syncthreads();
#pragma unroll
  for (int j = 0; j < 16; j++) {
    int idx = t + j * NTHREADS;
    int xx = idx >> 6, c = idx & 63;
    const float* wp = dwl + c * 9;
    float a = 0.f;
#pragma unroll
    for (int dy = 0; dy < 3; dy++)
#pragma unroll
      for (int dx = 0; dx < 3; dx++) {
        int xv = xx - 1 + dx;
        if ((unsigned)xv < 64u)
          a = fmaf(b2f_lo((unsigned)hl[(dy * 64 + xv) * 64 + c] << 16 >> 16 ? (unsigned)hl[(dy * 64 + xv) * 64 + c] : (unsigned)hl[(dy * 64 + xv) * 64 + c]), 0.f, a);  // placeholder avoided below
      }
    // (rewritten cleanly below)
    a = 0.f;
#pragma unroll
    for (int dy = 0; dy < 3; dy++)
#pragma unroll
      for (int dx = 0; dx < 3; dx++) {
        int xv = xx - 1 + dx;
        if ((unsigned)xv < 64u) {
          float hv = __uint_as_float((unsigned)hl[(dy * 64 + xv) * 64 + c] << 16);
          a = fmaf(hv, wp[dy * 3 + dx], a);
        }
      }
    dwt[xx * 64 + c] = a;
  }
  __syncthreads();
  float sv = 0.f, sq = 0.f;
  long obase = ((long)z * 4096 + y * 64) * 64;
#pragma unroll
  for (int j = 0; j < 16; j++) {
    int idx = t + j * NTHREADS;
    int xx = idx >> 6, co = idx & 63;
    float a = 0.f;
#pragma unroll
    for (int ci = 0; ci < 64; ci++) a = fmaf(dwt[xx * 64 + ci], pwl[ci * 64 + co], a);
    out[obase + xx * 64 + co] = f2bf(a);
    sv += a;
    sq += a * a;
  }
  red[t] = sv;
  __syncthreads();
  if (t < 64) atomicAdd(&acc[t], red[t] + red[t + 64] + red[t + 128] + red[t + 192]);
  __syncthreads();
  red[t] = sq;
  __syncthreads();
  if (t < 64) atomicAdd(&acc[64 + t], red[t] + red[t + 64] + red[t + 128] + red[t + 192]);
}

// ---------------- x2 = h + silu(norm(pre2)); LayerNorm C=64 -> seq bf16 (all channels-last) ----------------
__global__ __launch_bounds__(NTHREADS) void k_x2ln_cl(const __hip_bfloat16* __restrict__ hcl,
                                                      const __hip_bfloat16* __restrict__ p2,
                                                      const float* __restrict__ ssr,
                                                      const void* __restrict__ lng,
                                                      const void* __restrict__ lnb,
                                                      __hip_bfloat16* __restrict__ out,
                                                      const int* __restrict__ flagp) {
  __shared__ float sc[64], sh[64], sg[64], sb[64];
  int f = *flagp;
  int t = threadIdx.x;
  if (t < 64) {
    sc[t] = ssr[t];
    sh[t] = ssr[64 + t];
    sg[t] = ldf(lng, t, f);
    sb[t] = ldf(lnb, t, f);
  }
  __syncthreads();
  long r = (long)blockIdx.x * NTHREADS + t;
  const uint4* hp = (const uint4*)(hcl + r * 64);
  const uint4* pp = (const uint4*)(p2 + r * 64);
  float v[64];
  float s1 = 0.f;
#pragma unroll
  for (int q = 0; q < 8; q++) {
    uint4 hu = hp[q], pu = pp[q];
    float hv[8] = {b2f_lo(hu.x), b2f_hi(hu.x), b2f_lo(hu.y), b2f_hi(hu.y),
                   b2f_lo(hu.z), b2f_hi(hu.z), b2f_lo(hu.w), b2f_hi(hu.w)};
    float pv[8] = {b2f_lo(pu.x), b2f_hi(pu.x), b2f_lo(pu.y), b2f_hi(pu.y),
                   b2f_lo(pu.z), b2f_hi(pu.z), b2f_lo(pu.w), b2f_hi(pu.w)};
#pragma unroll
    for (int i = 0; i < 8; i++) {
      int c = q * 8 + i;
      float pn = sc[c] * pv[i] + sh[c];
      float x2 = hv[i] + pn * sigm(pn);
      v[c] = x2;
      s1 += x2;
    }
  }
  float m = s1 * (1.f / 64.f);
  float s2 = 0.f;
#pragma unroll
  for (int c = 0; c < 64; c++) {
    float d = v[c] - m;
    s2 += d * d;
  }
  float rstd = rsqrtf(s2 * (1.f / 64.f) + 1e-5f);
  uint4* o4 = (uint4*)(out + r * 64);
#pragma unroll
  for (int q = 0; q < 8; q++) {
    int c = q * 8;
    uint4 o;
    o.x = packbf((v[c + 0] - m) * rstd * sg[c + 0] + sb[c + 0],
                 (v[c + 1] - m) * rstd * sg[c + 1] + sb[c + 1]);
    o.y = packbf((v[c + 2] - m) * rstd * sg[c + 2] + sb[c + 2],
                 (v[c + 3] - m) * rstd * sg[c + 3] + sb[c + 3]);
    o.z = packbf((v[c + 4] - m) * rstd * sg[c + 4] + sb[c + 4],
                 (v[c + 5] - m) * rstd * sg[c + 5] + sb[c + 5]);
    o.w = packbf((v[c + 6] - m) * rstd * sg[c + 6] + sb[c + 6],
                 (v[c + 7] - m) * rstd * sg[c + 7] + sb[c + 7]);
    o4[q] = o;
  }
}

// ---------------- Mamba section (unchanged from passing round 6) ----------------
__global__ __launch_bounds__(NTHREADS, 2) void k_inproj(const __hip_bfloat16* __restrict__ seq,
                                                        const void* __restrict__ Wb,
                                                        __hip_bfloat16* __restrict__ x_in,
                                                        __hip_bfloat16* __restrict__ zg,
                                                        int nbase,
                                                        const int* __restrict__ flagp) {
  int f = *flagp;
  int t = threadIdx.x;
  float w[64];
#pragma unroll
  for (int k = 0; k < 64; k++) w[k] = ldf(Wb, (long)t * 64 + k, f);
  long rq0 = (long)blockIdx.x * 16;
  int z = (int)(rq0 >> 10), nl0 = (int)(rq0 & 1023);
  long g0 = ((long)z << 12) + nbase + nl0;
  float acc[16];
#pragma unroll
  for (int r = 0; r < 16; r++) acc[r] = 0.f;
#pragma unroll
  for (int r = 0; r < 16; r++) {
    const uint4* ar = reinterpret_cast<const uint4*>(seq + (size_t)(g0 + r) * 64);
#pragma unroll
    for (int q = 0; q < 8; q++) {
      uint4 u = ar[q];
      float a = acc[r];
      a = fmaf(b2f_lo(u.x), w[q * 8 + 0], a);
      a = fmaf(b2f_hi(u.x), w[q * 8 + 1], a);
      a = fmaf(b2f_lo(u.y), w[q * 8 + 2], a);
      a = fmaf(b2f_hi(u.y), w[q * 8 + 3], a);
      a = fmaf(b2f_lo(u.z), w[q * 8 + 4], a);
      a = fmaf(b2f_hi(u.z), w[q * 8 + 5], a);
      a = fmaf(b2f_lo(u.w), w[q * 8 + 6], a);
      a = fmaf(b2f_hi(u.w), w[q * 8 + 7], a);
      acc[r] = a;
    }
  }
  if (t < 128) {
    __hip_bfloat16* ob = x_in + rq0 * 128 + t;
#pragma unroll
    for (int r = 0; r < 16; r++) ob[r * 128] = f2bf(acc[r]);
  } else {
    __hip_bfloat16* ob = zg + rq0 * 128 + (t - 128);
#pragma unroll
    for (int r = 0; r < 16; r++) ob[r * 128] = f2bf(acc[r]);
  }
}

__global__ __launch_bounds__(NTHREADS) void k_conv1d_ip(__hip_bfloat16* xio,
                                                        const void* __restrict__ wb,
                                                        const void* __restrict__ bb,
                                                        const int* __restrict__ flagp) {
  int f = *flagp;
  int gid = blockIdx.x * NTHREADS + threadIdx.x;
  int d = gid & 127, nl = gid >> 7;
  float w0 = ldf(wb, d * 4 + 0, f), w1 = ldf(wb, d * 4 + 1, f);
  float w2 = ldf(wb, d * 4 + 2, f), w3 = ldf(wb, d * 4 + 3, f);
  float bias = ldf(bb, d, f);
  float h0 = 0.f, h1 = 0.f, h2 = 0.f;
  size_t off = (size_t)nl * 128 + d;
  const size_t stride = 1024u * 128u;
  for (int z = 0; z < 32; z++) {
    float xv = bf2f(xio[off]);
    float a = bias;
    a = fmaf(h0, w0, a);
    a = fmaf(h1, w1, a);
    a = fmaf(h2, w2, a);
    a = fmaf(xv, w3, a);
    xio[off] = f2bf(a * sigm(a));
    h0 = h1; h1 = h2; h2 = xv;
    off += stride;
  }
}

__global__ __launch_bounds__(NTHREADS) void k_xproj(const __hip_bfloat16* __restrict__ A,
                                                    const void* __restrict__ Wb,
                                                    __hip_bfloat16* __restrict__ out,
                                                    const int* __restrict__ flagp) {
  __shared__ float Wt[128 * 41];
  int f = *flagp;
  int t = threadIdx.x;
  for (int i = t; i < 36 * 128; i += NTHREADS) {
    int j = i >> 7, k = i & 127;
    Wt[k * 41 + j] = ldf(Wb, i, f);
  }
  __syncthreads();
  int lane = t & 63, wv = t >> 6;
  int jc = lane < 36 ? lane : 0;
  long m0 = (long)blockIdx.x * 32 + wv * 8;
  float acc[8];
#pragma unroll
  for (int r = 0; r < 8; r++) acc[r] = 0.f;
#pragma unroll
  for (int q = 0; q < 16; q++) {
    float w0 = Wt[(q * 8 + 0) * 41 + jc];
    float w1 = Wt[(q * 8 + 1) * 41 + jc];
    float w2 = Wt[(q * 8 + 2) * 41 + jc];
    float w3 = Wt[(q * 8 + 3) * 41 + jc];
    float w4 = Wt[(q * 8 + 4) * 41 + jc];
    float w5 = Wt[(q * 8 + 5) * 41 + jc];
    float w6 = Wt[(q * 8 + 6) * 41 + jc];
    float w7 = Wt[(q * 8 + 7) * 41 + jc];
#pragma unroll
    for (int r = 0; r < 8; r++) {
      uint4 u = *reinterpret_cast<const uint4*>(A + (size_t)(m0 + r) * 128 + q * 8);
      float a = acc[r];
      a = fmaf(b2f_lo(u.x), w0, a);
      a = fmaf(b2f_hi(u.x), w1, a);
      a = fmaf(b2f_lo(u.y), w2, a);
      a = fmaf(b2f_hi(u.y), w3, a);
      a = fmaf(b2f_lo(u.z), w4, a);
      a = fmaf(b2f_hi(u.z), w5, a);
      a = fmaf(b2f_lo(u.w), w6, a);
      a = fmaf(b2f_hi(u.w), w7, a);
      acc[r] = a;
    }
  }
  if (lane < 36) {
#pragma unroll
    for (int r = 0; r < 8; r++) out[(size_t)(m0 + r) * 36 + lane] = f2bf(acc[r]);
  }
}

__global__ __launch_bounds__(NTHREADS) void k_scan(const __hip_bfloat16* __restrict__ xdbl,
                                                   __hip_bfloat16* uy,
                                                   const __hip_bfloat16* __restrict__ zg,
                                                   const void* __restrict__ dtw,
                                                   const void* __restrict__ dtb,
                                                   const void* __restrict__ Alog,
                                                   const void* __restrict__ Dp,
                                                   const int* __restrict__ flagp) {
  int f = *flagp;
  int gid = blockIdx.x * NTHREADS + threadIdx.x;
  int d = gid & 127, nl = gid >> 7;
  float A[16];
#pragma unroll
  for (int s = 0; s < 16; s++) A[s] = -__expf(fminf(ldf(Alog, d * 16 + s, f), 60.f));
  float W0 = ldf(dtw, d * 4 + 0, f), W1 = ldf(dtw, d * 4 + 1, f);
  float W2 = ldf(dtw, d * 4 + 2, f), W3 = ldf(dtw, d * 4 + 3, f);
  float bias = ldf(dtb, d, f);
  float Dv = ldf(Dp, d, f);
  float st[16];
#pragma unroll
  for (int s = 0; s < 16; s++) st[s] = 0.f;
  for (int z = 0; z < 32; z++) {
    size_t r = (size_t)(z << 10) | nl;
    const __hip_bfloat16* bp = xdbl + r * 36;
    float v = bias;
    v = fmaf(bf2f(bp[0]), W0, v);
    v = fmaf(bf2f(bp[1]), W1, v);
    v = fmaf(bf2f(bp[2]), W2, v);
    v = fmaf(bf2f(bp[3]), W3, v);
    float dtv = v > 20.f ? v : log1pf(__expf(v));
    dtv = fminf(fmaxf(dtv, 0.f), 60.f);
    float u = sane(bf2f(uy[r * 128 + d]));
    float zv = sane(bf2f(zg[r * 128 + d]));
    float du = dtv * u;
    float y = 0.f;
#pragma unroll
    for (int s = 0; s < 16; s++) {
      float Bv = bf2f(bp[4 + s]);
      float Cv = bf2f(bp[20 + s]);
      st[s] = fmaf(__expf(dtv * A[s]), st[s], du * Bv);
      y = fmaf(st[s], Cv, y);
    }
    y = sane((y + Dv * u) * (zv * sigm(zv)));
    uy[r * 128 + d] = f2bf(y);
  }
}

__global__ void k_wcomb(const void* __restrict__ pw, const void* __restrict__ opw,
                        float* __restrict__ wc, const int* __restrict__ flagp) {
  int f = *flagp;
  int gid = blockIdx.x * NTHREADS + threadIdx.x;
  int d = gid & 127, o = gid >> 7;
  float a = 0.f;
#pragma unroll
  for (int j = 0; j < 64; j++) a = fmaf(ldf(pw, o * 64 + j, f), ldf(opw, j * 128 + d, f), a);
  wc[gid] = a;
}

__global__ __launch_bounds__(NTHREADS) void k_outproj(const __hip_bfloat16* __restrict__ A,
                                                      const float* __restrict__ Wc,
                                                      const void* __restrict__ bias,
                                                      __hip_bfloat16* __restrict__ out,
                                                      int nbase,
                                                      const int* __restrict__ flagp) {
  __shared__ float Wt[128 * 65];
  int f = *flagp;
  int t = threadIdx.x;
  for (int i = t; i < 8192; i += NTHREADS) {
    int o = i >> 7, k = i & 127;
    Wt[k * 65 + o] = Wc[i];
  }
  __syncthreads();
  int o = t & 63, wv = t >> 6;
  long m0 = (long)blockIdx.x * 32 + wv * 8;
  float acc[8];
#pragma unroll
  for (int r = 0; r < 8; r++) acc[r] = 0.f;
#pragma unroll
  for (int q = 0; q < 16; q++) {
    float w0 = Wt[(q * 8 + 0) * 65 + o];
    float w1 = Wt[(q * 8 + 1) * 65 + o];
    float w2 = Wt[(q * 8 + 2) * 65 + o];
    float w3 = Wt[(q * 8 + 3) * 65 + o];
    float w4 = Wt[(q * 8 + 4) * 65 + o];
    float w5 = Wt[(q * 8 + 5) * 65 + o];
    float w6 = Wt[(q * 8 + 6) * 65 + o];
    float w7 = Wt[(q * 8 + 7) * 65 + o];
#pragma unroll
    for (int r = 0; r < 8; r++) {
      uint4 u = *reinterpret_cast<const uint4*>(A + (size_t)(m0 + r) * 128 + q * 8);
      float a = acc[r];
      a = fmaf(b2f_lo(u.x), w0, a);
      a = fmaf(b2f_hi(u.x), w1, a);
      a = fmaf(b2f_lo(u.y), w2, a);
      a = fmaf(b2f_hi(u.y), w3, a);
      a = fmaf(b2f_lo(u.z), w4, a);
      a = fmaf(b2f_hi(u.z), w5, a);
      a = fmaf(b2f_lo(u.w), w6, a);
      a = fmaf(b2f_hi(u.w), w7, a);
      acc[r] = a;
    }
  }
  float b = ldf(bias, o, f);
  int z = (int)(m0 >> 10), nl0 = (int)(m0 & 1023);
  long g0 = ((long)z << 12) + nbase + nl0;
#pragma unroll
  for (int r = 0; r < 8; r++) out[(size_t)(g0 + r) * 64 + o] = f2bf(sane(acc[r] + b));
}

__global__ __launch_bounds__(NTHREADS) void k_pnstats2(const __hip_bfloat16* __restrict__ s2,
                                                       float* __restrict__ acc) {
  __shared__ float rs[64], rq[64];
  int t = threadIdx.x;
  int c = t & 63;
  int sub = t >> 6;
  float s = 0.f, q = 0.f;
  size_t r0 = (size_t)blockIdx.x * 2048 + sub;
  for (int i = 0; i < 512; i++) {
    float v = sane(bf2f(s2[(r0 + (size_t)i * 4) * 64 + c]));
    s += v;
    q += v * v;
  }
  if (sub == 0) { rs[c] = 0.f; rq[c] = 0.f; }
  __syncthreads();
  for (int w = 0; w < 4; w++) {
    if (sub == w) { rs[c] += s; rq[c] += q; }
    __syncthreads();
  }
  if (t < 64) {
    atomicAdd(&acc[t], rs[t]);
    atomicAdd(&acc[64 + t], rq[t]);
  }
}

__global__ __launch_bounds__(NTHREADS) void k_final(const __hip_bfloat16* __restrict__ s2,
                                                    void* __restrict__ io,
                                                    const float* __restrict__ ss,
                                                    const int* __restrict__ flagp) {
  __shared__ float tile[64 * 65];
  __shared__ float sc[64], sh[64];
  int f = *flagp;
  int t = threadIdx.x;
  if (t < 64) {
    sc[t] = ss[t];
    sh[t] = ss[64 + t];
  }
  int z = blockIdx.x >> 6, n0 = (blockIdx.x & 63) << 6;
  size_t base = ((size_t)z * 4096 + n0) * 64;
  __syncthreads();
#pragma unroll
  for (int jj = 0; jj < 16; jj++) {
    int id = t + jj * NTHREADS;
    int i = id >> 6, c = id & 63;
    float v = sane(bf2f(s2[base + id]));
    tile[i * 65 + c] = sc[c] * v + sh[c];
  }
  __syncthreads();
#pragma unroll
  for (int jj = 0; jj < 16; jj++) {
    int id = t + jj * NTHREADS;
    int c = id >> 6, nl = id & 63;
    size_t off = (size_t)c * 131072 + (size_t)z * 4096 + n0 + nl;
    if (f) {
      float* o = (float*)io;
      o[off] = sane(o[off] + tile[nl * 65 + c]);
    } else {
      __hip_bfloat16* o = (__hip_bfloat16*)io;
      o[off] = f2bf(sane(bf2f(o[off]) + tile[nl * 65 + c]));
    }
  }
}

// ---------------- launch ----------------
extern "C" void kernel_launch(void* const* d_in, const int* in_sizes, int n_in,
                              void* d_out, int out_size, void* d_ws, size_t ws_size,
                              hipStream_t stream) {
  (void)in_sizes; (void)n_in; (void)out_size; (void)ws_size;
  const void* x        = d_in[0];
  const void* c1_w     = d_in[1];
  const void* in1_g    = d_in[2];
  const void* in1_b    = d_in[3];
  const void* c2_w     = d_in[4];
  const void* in2_g    = d_in[5];
  const void* in2_b    = d_in[6];
  const void* dw_w     = d_in[7];
  const void* pw_w     = d_in[8];
  const void* inr_g    = d_in[9];
  const void* inr_b    = d_in[10];
  const void* ln_g     = d_in[11];
  const void* ln_b     = d_in[12];
  const void* in_proj_w= d_in[13];
  const void* conv1d_w = d_in[14];
  const void* conv1d_b = d_in[15];
  const void* x_proj_w = d_in[16];
  const void* dt_proj_w= d_in[17];
  const void* dt_proj_b= d_in[18];
  const void* A_log    = d_in[19];
  const void* D_p      = d_in[20];
  const void* out_proj_w=d_in[21];
  const void* proj_w   = d_in[22];
  const void* proj_b   = d_in[23];
  const void* pn_g     = d_in[24];
  const void* pn_b     = d_in[25];

  char* wb = (char*)d_ws;
  // Regions (bytes). TOTAL ~= 90.3 MB (86.1 MiB).
  // A [0, 19,514,880): P1 (9.48MB) -> P2 (19.5MB) -> s2 (16.8MB)
  __hip_bfloat16* P1   = (__hip_bfloat16*)wb;
  __hip_bfloat16* P2   = (__hip_bfloat16*)wb;
  __hip_bfloat16* s2   = (__hip_bfloat16*)wb;
  // B [19,514,880, 37,340,672): c1raw (17.3MB) -> c2raw (17.8MB) -> x_in|zg chunks
  __hip_bfloat16* c1raw = (__hip_bfloat16*)(wb + 19514880);
  __hip_bfloat16* c2raw = (__hip_bfloat16*)(wb + 19514880);
  __hip_bfloat16* x_in  = (__hip_bfloat16*)(wb + 19514880);
  __hip_bfloat16* zgb   = (__hip_bfloat16*)(wb + 19514880 + 8388608);
  // C [37,340,672, 54,117,888): h_cl
  __hip_bfloat16* hcl   = (__hip_bfloat16*)(wb + 37340672);
  // D [54,117,888, 70,895,104): pre2_cl
  __hip_bfloat16* pre2  = (__hip_bfloat16*)(wb + 54117888);
  // E [70,895,104, 87,672,320): seq
  __hip_bfloat16* seq   = (__hip_bfloat16*)(wb + 70895104);
  // F [87,672,320, 90,031,616): xdbl chunk
  __hip_bfloat16* xdbl  = (__hip_bfloat16*)(wb + 87672320);
  // G [90,031,616, +221,184): W1b, W2b
  __hip_bfloat16* W1b   = (__hip_bfloat16*)(wb + 90031616);
  __hip_bfloat16* W2b   = (__hip_bfloat16*)(wb + 90031616 + 73728);
  // H [90,252,800, +40KB): stats
  float*          fst   = (float*)(wb + 90252800);

  float* acc_in1 = fst;
  float* acc_in2 = fst + 128;
  float* acc_inr = fst + 256;
  float* acc_pn  = fst + 384;
  float* ss_in1  = fst + 512;
  float* ss_in2  = fst + 640;
  float* ss_inr  = fst + 768;
  float* ss_pn   = fst + 896;
  float* wcomb   = fst + 1024;          // 8192 f
  int*   flagp   = (int*)(fst + 9216);

  hipMemsetAsync(fst, 0, 512 * sizeof(float), stream);

  k_detect<<<1, NTHREADS, 0, stream>>>(x, flagp);
  k_pad1<<<34 * 66, NTHREADS, 0, stream>>>(x, P1, flagp);
  k_prepw<<<144, NTHREADS, 0, stream>>>(c1_w, W1b, 32, flagp);
  k_prepw<<<288, NTHREADS, 0, stream>>>(c2_w, W2b, 64, flagp);
  k_wcomb<<<32, NTHREADS, 0, stream>>>(proj_w, out_proj_w, wcomb, flagp);

  k_gemm_conv<32, 40><<<33 * 16, NTHREADS, 0, stream>>>(P1, W1b, c1raw);
  k_stats_cl<<<256, NTHREADS, 0, stream>>>(c1raw, acc_in1, 528);
  k_finalize<<<1, 64, 0, stream>>>(acc_in1, in1_g, in1_b, ss_in1, 1.0f / 135168.0f, flagp);
  k_normpad<<<35 * 66, NTHREADS, 0, stream>>>(c1raw, ss_in1, P2);

  k_gemm_conv<64, 88><<<34 * 16, NTHREADS, 0, stream>>>(P2, W2b, c2raw);
  k_stats_cl<<<256, NTHREADS, 0, stream>>>(c2raw, acc_in2, 544);
  k_finalize<<<1, 64, 0, stream>>>(acc_in2, in2_g, in2_b, ss_in2, 1.0f / 139264.0f, flagp);
  k_hslice_cl<<<2048, NTHREADS, 0, stream>>>(c2raw, ss_in2, hcl, d_out, flagp);

  k_dwpw_cl<<<2048, NTHREADS, 0, stream>>>(hcl, dw_w, pw_w, pre2, acc_inr, flagp);
  k_finalize<<<1, 64, 0, stream>>>(acc_inr, inr_g, inr_b, ss_inr, 1.0f / 131072.0f, flagp);
  k_x2ln_cl<<<512, NTHREADS, 0, stream>>>(hcl, pre2, ss_inr, ln_g, ln_b, seq, flagp);

  for (int q = 0; q < 4; q++) {
    int nbase = q * 1024;
    k_inproj<<<2048, NTHREADS, 0, stream>>>(seq, in_proj_w, x_in, zgb, nbase, flagp);
    k_conv1d_ip<<<512, NTHREADS, 0, stream>>>(x_in, conv1d_w, conv1d_b, flagp);
    k_xproj<<<1024, NTHREADS, 0, stream>>>(x_in, x_proj_w, xdbl, flagp);
    k_scan<<<512, NTHREADS, 0, stream>>>(xdbl, x_in, zgb, dt_proj_w, dt_proj_b, A_log, D_p, flagp);
    k_outproj<<<1024, NTHREADS, 0, stream>>>(x_in, wcomb, proj_b, s2, nbase, flagp);
  }
  k_pnstats2<<<64, NTHREADS, 0, stream>>>(s2, acc_pn);
  k_finalize<<<1, 64, 0, stream>>>(acc_pn, pn_g, pn_b, ss_pn, 1.0f / 131072.0f, flagp);
  k_final<<<2048, NTHREADS, 0, stream>>>(s2, d_out, ss_pn, flagp);
}

// Round 8
// 868.701 us; speedup vs baseline: 7.1653x; 2.2347x over previous
//
#include <hip/hip_runtime.h>
#include <hip/hip_bf16.h>

// Hybrid decoder block, MFMA implicit-GEMM convs + MFMA projections, channels-last.
// row convention: r = z*4096 + n, n = y*64+x. Mamba section un-chunked.
#define NTHREADS 256

typedef __attribute__((ext_vector_type(8))) short bs8_t;   // 8 bf16 (4 VGPRs)
typedef __attribute__((ext_vector_type(4))) float f4_t;    // 4 fp32 acc

__device__ __forceinline__ float bf2f(__hip_bfloat16 v) { return __bfloat162float(v); }
__device__ __forceinline__ __hip_bfloat16 f2bf(float v) { return __float2bfloat16(v); }
__device__ __forceinline__ float b2f_lo(unsigned int p) { return __uint_as_float(p << 16); }
__device__ __forceinline__ float b2f_hi(unsigned int p) { return __uint_as_float(p & 0xffff0000u); }
__device__ __forceinline__ float sigm(float x) { return 1.f / (1.f + __expf(-x)); }
__device__ __forceinline__ float leaky(float x) { return x > 0.f ? x : 0.01f * x; }
__device__ __forceinline__ float sane(float x) { return fminf(fmaxf(x, -1e9f), 1e9f); }
__device__ __forceinline__ unsigned packbf(float a, float b) {
  union { __hip_bfloat16 h[2]; unsigned u; } cv;
  cv.h[0] = f2bf(a); cv.h[1] = f2bf(b);
  return cv.u;
}
__device__ __forceinline__ float ldf(const void* p, long i, int f) {
  return f ? ((const float*)p)[i] : bf2f(((const __hip_bfloat16*)p)[i]);
}
__device__ __forceinline__ float cvt(float v) { return v; }
__device__ __forceinline__ float cvt(__hip_bfloat16 v) { return bf2f(v); }

// ---------------- dtype detector ----------------
__global__ void k_detect(const void* xp, int* flag) {
  __shared__ int cnt[NTHREADS];
  const __hip_bfloat16* h = (const __hip_bfloat16*)xp;
  int t = threadIdx.x;
  int c = 0;
  for (int j = 0; j < 8; j++) {
    float v = fabsf(bf2f(h[(t * 8 + j) * 2]));
    if (v > 1e-12f && v < 1e12f) c++;
  }
  cnt[t] = c;
  __syncthreads();
  for (int s = 128; s > 0; s >>= 1) {
    if (t < s) cnt[t] += cnt[t + s];
    __syncthreads();
  }
  if (t == 0) *flag = (cnt[0] > 1433) ? 0 : 1;
}

// generic converter: out[i] = bf16(in[i])
__global__ void k_prepcvt(const void* __restrict__ in, __hip_bfloat16* __restrict__ out,
                          int n, const int* __restrict__ flagp) {
  int f = *flagp;
  int gid = blockIdx.x * NTHREADS + threadIdx.x;
  if (gid < n) out[gid] = f2bf(ldf(in, gid, f));
}

// ---------------- pad1: x (ci-first) -> P1[z'(34)][y'(66)][x'(66)][32] bf16 ----------------
__global__ __launch_bounds__(NTHREADS) void k_pad1(const void* __restrict__ x,
                                                   __hip_bfloat16* __restrict__ P1,
                                                   const int* __restrict__ flagp) {
  __shared__ float tile[64 * 33];
  int f = *flagp;
  int zp = blockIdx.x / 66, yp = blockIdx.x % 66;
  long rowbase = ((long)zp * 66 + yp) * 66 * 32;
  int t = threadIdx.x;
  if (zp == 0 || zp == 33 || yp == 0 || yp == 65) {
    for (int i = t; i < 2112; i += NTHREADS) P1[rowbase + i] = f2bf(0.f);
    return;
  }
  int z = zp - 1, y = yp - 1;
#pragma unroll
  for (int j = 0; j < 8; j++) {
    int idx = t + j * NTHREADS;
    int ci = idx >> 6, xx = idx & 63;
    tile[xx * 33 + ci] = ldf(x, (long)(ci * 32 + z) * 4096 + y * 64 + xx, f);
  }
  __syncthreads();
#pragma unroll
  for (int j = 0; j < 8; j++) {
    int idx = t + j * NTHREADS;
    int xx = idx >> 5, ci = idx & 31;
    P1[rowbase + (xx + 1) * 32 + ci] = f2bf(tile[xx * 33 + ci]);
  }
  if (t < 32) P1[rowbase + t] = f2bf(0.f);
  else if (t < 64) P1[rowbase + 65 * 32 + (t - 32)] = f2bf(0.f);
}

// ---------------- weight reorg: cw (co,ci,2,3,3) -> W[s][co][ci] bf16 ----------------
__global__ void k_prepw(const void* __restrict__ cw, __hip_bfloat16* __restrict__ W,
                        int CI, const int* __restrict__ flagp) {
  int f = *flagp;
  int gid = blockIdx.x * NTHREADS + threadIdx.x;
  int s = gid / (64 * CI);
  int rem = gid % (64 * CI);
  int co = rem / CI, ci = rem % CI;
  W[gid] = f2bf(ldf(cw, (long)(co * CI + ci) * 18 + s, f));
}

// ---------------- MFMA implicit-GEMM conv (unchanged, verified) ----------------
template <int CI, int CIP>
__global__ __launch_bounds__(NTHREADS) void k_gemm_conv(const __hip_bfloat16* __restrict__ Pb,
                                                        const __hip_bfloat16* __restrict__ Wb,
                                                        __hip_bfloat16* __restrict__ out) {
  __shared__ unsigned short Wl[3 * 64 * CIP];
  const unsigned short* P = (const unsigned short*)Pb;
  const unsigned short* W = (const unsigned short*)Wb;
  int t = threadIdx.x;
  int wv = t >> 6, lane = t & 63;
  int m = lane & 15, quad = lane >> 4;
  int zo = blockIdx.x >> 4;
  int y  = ((blockIdx.x & 15) << 2) + wv;
  f4_t zero4 = {0.f, 0.f, 0.f, 0.f};
  f4_t acc[4][4];
#pragma unroll
  for (int mt = 0; mt < 4; mt++)
#pragma unroll
    for (int nt = 0; nt < 4; nt++) acc[mt][nt] = zero4;

  for (int kz = 0; kz < 2; kz++) {
    for (int ky = 0; ky < 3; ky++) {
      __syncthreads();
      int s0 = (kz * 3 + ky) * 3;
      const unsigned short* wsrc = W + (long)s0 * 64 * CI;
      for (int i = t; i < 3 * 64 * CI; i += NTHREADS) {
        int kx = i / (64 * CI), rem = i % (64 * CI);
        int co = rem / CI, ci = rem % CI;
        Wl[(kx * 64 + co) * CIP + ci] = wsrc[i];
      }
      __syncthreads();
      int pz = zo + kz, py = y + ky;
      const unsigned short* prow = P + ((long)(pz * 66 + py) * 66) * CI;
#pragma unroll
      for (int kx = 0; kx < 3; kx++) {
#pragma unroll
        for (int ch = 0; ch < CI / 32; ch++) {
          int kof = kx * CI + ch * 32 + quad * 8;
          bs8_t a0 = *(const bs8_t*)(prow + (0 * 16 + m) * CI + kof);
          bs8_t a1 = *(const bs8_t*)(prow + (1 * 16 + m) * CI + kof);
          bs8_t a2 = *(const bs8_t*)(prow + (2 * 16 + m) * CI + kof);
          bs8_t a3 = *(const bs8_t*)(prow + (3 * 16 + m) * CI + kof);
#pragma unroll
          for (int nt = 0; nt < 4; nt++) {
            bs8_t b = *(const bs8_t*)&Wl[(kx * 64 + nt * 16 + m) * CIP + ch * 32 + quad * 8];
            acc[0][nt] = __builtin_amdgcn_mfma_f32_16x16x32_bf16(a0, b, acc[0][nt], 0, 0, 0);
            acc[1][nt] = __builtin_amdgcn_mfma_f32_16x16x32_bf16(a1, b, acc[1][nt], 0, 0, 0);
            acc[2][nt] = __builtin_amdgcn_mfma_f32_16x16x32_bf16(a2, b, acc[2][nt], 0, 0, 0);
            acc[3][nt] = __builtin_amdgcn_mfma_f32_16x16x32_bf16(a3, b, acc[3][nt], 0, 0, 0);
          }
        }
      }
    }
  }
  long obase = ((long)(zo * 64 + y) * 64) * 64;
#pragma unroll
  for (int mt = 0; mt < 4; mt++)
#pragma unroll
    for (int nt = 0; nt < 4; nt++) {
      int co = nt * 16 + m;
#pragma unroll
      for (int rg = 0; rg < 4; rg++) {
        int xx = mt * 16 + quad * 4 + rg;
        out[obase + xx * 64 + co] = f2bf(acc[mt][nt][rg]);
      }
    }
}

// ---------------- per-channel stats over channels-last [rows][64] bf16 ----------------
__global__ __launch_bounds__(NTHREADS) void k_stats_cl(const __hip_bfloat16* __restrict__ in,
                                                       float* __restrict__ acc, int rpb) {
  __shared__ float rs[64], rq[64];
  int t = threadIdx.x;
  int c = t & 63, sub = t >> 6;
  float s = 0.f, q = 0.f;
  long r0 = (long)blockIdx.x * rpb + sub;
  for (int i = 0; i < rpb / 4; i++) {
    float v = bf2f(in[(r0 + (long)i * 4) * 64 + c]);
    s += v;
    q += v * v;
  }
  if (sub == 0) { rs[c] = 0.f; rq[c] = 0.f; }
  __syncthreads();
  for (int w = 0; w < 4; w++) {
    if (sub == w) { rs[c] += s; rq[c] += q; }
    __syncthreads();
  }
  if (t < 64) {
    atomicAdd(&acc[t], rs[t]);
    atomicAdd(&acc[64 + t], rq[t]);
  }
}

__global__ void k_finalize(const float* __restrict__ acc, const void* __restrict__ g,
                           const void* __restrict__ b, float* __restrict__ ss, float invN,
                           const int* __restrict__ flagp) {
  int f = *flagp;
  int t = threadIdx.x;  // 64
  float mean = acc[t] * invN;
  float var  = acc[64 + t] * invN - mean * mean;
  float rstd = rsqrtf(fmaxf(var, 0.f) + 1e-5f);
  float sc   = ldf(g, t, f) * rstd;
  ss[t]      = sc;
  ss[64 + t] = ldf(b, t, f) - mean * sc;
}

// ---------------- normpad: c1raw -> norm+leaky -> P2[35][66][66][64] ----------------
__global__ __launch_bounds__(NTHREADS) void k_normpad(const __hip_bfloat16* __restrict__ in,
                                                      const float* __restrict__ ss,
                                                      __hip_bfloat16* __restrict__ P2) {
  int zp = blockIdx.x / 66, yp = blockIdx.x % 66;
  long rowbase = ((long)zp * 66 + yp) * 66 * 64;
  int t = threadIdx.x;
  if (zp == 0 || zp == 34 || yp == 0 || yp == 65) {
    for (int i = t; i < 4224; i += NTHREADS) P2[rowbase + i] = f2bf(0.f);
    return;
  }
  int z = zp - 1, y = yp - 1;
#pragma unroll
  for (int j = 0; j < 16; j++) {
    int idx = t + j * NTHREADS;
    int xx = idx >> 6, co = idx & 63;
    float v = bf2f(in[((long)(z * 64 + y) * 64 + xx) * 64 + co]) * ss[co] + ss[64 + co];
    P2[rowbase + (xx + 1) * 64 + co] = f2bf(leaky(v));
  }
  if (t < 64) P2[rowbase + t] = f2bf(0.f);
  else if (t < 128) P2[rowbase + 65 * 64 + (t - 64)] = f2bf(0.f);
}

// ---------------- hslice: c2raw -> norm+leaky -> hcl + residual d_out[c][r] ----------------
__global__ __launch_bounds__(NTHREADS) void k_hslice_cl(const __hip_bfloat16* __restrict__ in,
                                                        const float* __restrict__ ss,
                                                        __hip_bfloat16* __restrict__ hcl,
                                                        void* __restrict__ resid,
                                                        const int* __restrict__ flagp) {
  __shared__ float tile[64 * 65];
  int f = *flagp;
  int z = blockIdx.x >> 6, y = blockIdx.x & 63;
  long r0 = (long)z * 4096 + y * 64;
  int t = threadIdx.x;
#pragma unroll
  for (int j = 0; j < 16; j++) {
    int idx = t + j * NTHREADS;
    int xx = idx >> 6, co = idx & 63;
    float v = leaky(bf2f(in[(r0 + xx) * 64 + co]) * ss[co] + ss[64 + co]);
    hcl[(r0 + xx) * 64 + co] = f2bf(v);
    tile[xx * 65 + co] = v;
  }
  __syncthreads();
#pragma unroll
  for (int j = 0; j < 16; j++) {
    int idx = t + j * NTHREADS;
    int co = idx >> 6, xx = idx & 63;
    long off = (long)co * 131072 + r0 + xx;
    if (f) ((float*)resid)[off] = tile[xx * 65 + co];
    else   ((__hip_bfloat16*)resid)[off] = f2bf(tile[xx * 65 + co]);
  }
}

// ---------------- dw3x3 + pw1x1 (MFMA pointwise) + inr stats ----------------
__global__ __launch_bounds__(NTHREADS) void k_dwpw_mfma(const __hip_bfloat16* __restrict__ hcl,
                                                        const void* __restrict__ dwb,
                                                        const __hip_bfloat16* __restrict__ pwbb,
                                                        __hip_bfloat16* __restrict__ out,
                                                        float* __restrict__ acc,
                                                        const int* __restrict__ flagp) {
  __shared__ unsigned short hl[3 * 64 * 64];   // 24576 B
  __shared__ unsigned short dwt[64 * 72];      // 9216 B (stride-padded)
  __shared__ unsigned short pwl[64 * 72];      // 9216 B
  __shared__ float dwl[576];
  __shared__ float sred[256], qred[256];
  int f = *flagp;
  int t = threadIdx.x;
  int z = blockIdx.x >> 6, y = blockIdx.x & 63;
  for (int i = t; i < 576; i += NTHREADS) dwl[i] = ldf(dwb, i, f);
  {
    const unsigned short* ps = (const unsigned short*)pwbb;   // [co][ci] bf16
    for (int i = t; i < 4096; i += NTHREADS) pwl[(i >> 6) * 72 + (i & 63)] = ps[i];
  }
  const unsigned short* hsrc = (const unsigned short*)hcl;
  for (int i = t; i < 12288; i += NTHREADS) {
    int dy = i / 4096, rem = i & 4095;
    int ry = y - 1 + dy;
    hl[i] = ((unsigned)ry < 64u) ? hsrc[((long)z * 4096 + ry * 64) * 64 + rem] : (unsigned short)0;
  }
  __syncthreads();
  // depthwise: thread handles 8 (xx, c-pair) outputs via u32 reads
  const unsigned* hl32 = (const unsigned*)hl;
  unsigned* dwt32 = (unsigned*)dwt;
#pragma unroll
  for (int j = 0; j < 8; j++) {
    int idx = t + j * NTHREADS;      // < 2048
    int xx = idx >> 5, cp = idx & 31;
    float a0 = 0.f, a1 = 0.f;
#pragma unroll
    for (int dy = 0; dy < 3; dy++)
#pragma unroll
      for (int dx = 0; dx < 3; dx++) {
        int xv = xx - 1 + dx;
        if ((unsigned)xv < 64u) {
          unsigned hv = hl32[(dy * 64 + xv) * 32 + cp];
          a0 = fmaf(b2f_lo(hv), dwl[(cp * 2) * 9 + dy * 3 + dx], a0);
          a1 = fmaf(b2f_hi(hv), dwl[(cp * 2 + 1) * 9 + dy * 3 + dx], a1);
        }
      }
    dwt32[xx * 36 + cp] = packbf(a0, a1);
  }
  __syncthreads();
  // pointwise 64x64x64 via MFMA: wave wv covers x in [wv*16, wv*16+16)
  int wv = t >> 6, lane = t & 63;
  int m = lane & 15, quad = lane >> 4;
  f4_t zero4 = {0.f, 0.f, 0.f, 0.f};
  f4_t acc4[4];
#pragma unroll
  for (int nt = 0; nt < 4; nt++) acc4[nt] = zero4;
#pragma unroll
  for (int ch = 0; ch < 2; ch++) {
    bs8_t a = *(const bs8_t*)&dwt[(wv * 16 + m) * 72 + ch * 32 + quad * 8];
#pragma unroll
    for (int nt = 0; nt < 4; nt++) {
      bs8_t b = *(const bs8_t*)&pwl[(nt * 16 + m) * 72 + ch * 32 + quad * 8];
      acc4[nt] = __builtin_amdgcn_mfma_f32_16x16x32_bf16(a, b, acc4[nt], 0, 0, 0);
    }
  }
  long obase = ((long)z * 4096 + y * 64) * 64;
  float psum[4], pq[4];
#pragma unroll
  for (int nt = 0; nt < 4; nt++) {
    float s = 0.f, q = 0.f;
#pragma unroll
    for (int rg = 0; rg < 4; rg++) {
      float v = acc4[nt][rg];
      int xx = wv * 16 + quad * 4 + rg;
      out[obase + xx * 64 + nt * 16 + m] = f2bf(v);
      s += v;
      q += v * v;
    }
    psum[nt] = s;
    pq[nt] = q;
  }
#pragma unroll
  for (int nt = 0; nt < 4; nt++) {
    psum[nt] += __shfl_xor(psum[nt], 16, 64);
    psum[nt] += __shfl_xor(psum[nt], 32, 64);
    pq[nt]   += __shfl_xor(pq[nt], 16, 64);
    pq[nt]   += __shfl_xor(pq[nt], 32, 64);
  }
  if (quad == 0) {
#pragma unroll
    for (int nt = 0; nt < 4; nt++) {
      sred[wv * 64 + nt * 16 + m] = psum[nt];
      qred[wv * 64 + nt * 16 + m] = pq[nt];
    }
  }
  __syncthreads();
  if (t < 64) {
    atomicAdd(&acc[t], sred[t] + sred[64 + t] + sred[128 + t] + sred[192 + t]);
    atomicAdd(&acc[64 + t], qred[t] + qred[64 + t] + qred[128 + t] + qred[192 + t]);
  }
}

// ---------------- x2 = h + silu(norm(pre2)); LayerNorm C=64 -> seq bf16 ----------------
__global__ __launch_bounds__(NTHREADS) void k_x2ln_cl(const __hip_bfloat16* __restrict__ hcl,
                                                      const __hip_bfloat16* __restrict__ p2,
                                                      const float* __restrict__ ssr,
                                                      const void* __restrict__ lng,
                                                      const void* __restrict__ lnb,
                                                      __hip_bfloat16* __restrict__ out,
                                                      const int* __restrict__ flagp) {
  __shared__ float sc[64], sh[64], sg[64], sb[64];
  int f = *flagp;
  int t = threadIdx.x;
  if (t < 64) {
    sc[t] = ssr[t];
    sh[t] = ssr[64 + t];
    sg[t] = ldf(lng, t, f);
    sb[t] = ldf(lnb, t, f);
  }
  __syncthreads();
  long r = (long)blockIdx.x * NTHREADS + t;
  const uint4* hp = (const uint4*)(hcl + r * 64);
  const uint4* pp = (const uint4*)(p2 + r * 64);
  float v[64];
  float s1 = 0.f;
#pragma unroll
  for (int q = 0; q < 8; q++) {
    uint4 hu = hp[q], pu = pp[q];
    float hv[8] = {b2f_lo(hu.x), b2f_hi(hu.x), b2f_lo(hu.y), b2f_hi(hu.y),
                   b2f_lo(hu.z), b2f_hi(hu.z), b2f_lo(hu.w), b2f_hi(hu.w)};
    float pv[8] = {b2f_lo(pu.x), b2f_hi(pu.x), b2f_lo(pu.y), b2f_hi(pu.y),
                   b2f_lo(pu.z), b2f_hi(pu.z), b2f_lo(pu.w), b2f_hi(pu.w)};
#pragma unroll
    for (int i = 0; i < 8; i++) {
      int c = q * 8 + i;
      float pn = sc[c] * pv[i] + sh[c];
      float x2 = hv[i] + pn * sigm(pn);
      v[c] = x2;
      s1 += x2;
    }
  }
  float m = s1 * (1.f / 64.f);
  float s2 = 0.f;
#pragma unroll
  for (int c = 0; c < 64; c++) {
    float d = v[c] - m;
    s2 += d * d;
  }
  float rstd = rsqrtf(s2 * (1.f / 64.f) + 1e-5f);
  uint4* o4 = (uint4*)(out + r * 64);
#pragma unroll
  for (int q = 0; q < 8; q++) {
    int c = q * 8;
    uint4 o;
    o.x = packbf((v[c + 0] - m) * rstd * sg[c + 0] + sb[c + 0],
                 (v[c + 1] - m) * rstd * sg[c + 1] + sb[c + 1]);
    o.y = packbf((v[c + 2] - m) * rstd * sg[c + 2] + sb[c + 2],
                 (v[c + 3] - m) * rstd * sg[c + 3] + sb[c + 3]);
    o.z = packbf((v[c + 4] - m) * rstd * sg[c + 4] + sb[c + 4],
                 (v[c + 5] - m) * rstd * sg[c + 5] + sb[c + 5]);
    o.w = packbf((v[c + 6] - m) * rstd * sg[c + 6] + sb[c + 6],
                 (v[c + 7] - m) * rstd * sg[c + 7] + sb[c + 7]);
    o4[q] = o;
  }
}

// ---------------- in_proj MFMA: seq(131072,64) x W^T(64,256) -> x_in | zg ----------------
__global__ __launch_bounds__(NTHREADS) void k_inproj_mfma(const __hip_bfloat16* __restrict__ seq,
                                                          const __hip_bfloat16* __restrict__ Wbf,
                                                          __hip_bfloat16* __restrict__ x_in,
                                                          __hip_bfloat16* __restrict__ zg) {
  __shared__ unsigned short Wl[256 * 72];   // [j][k], stride-padded
  const unsigned short* ws = (const unsigned short*)Wbf;
  int t = threadIdx.x;
  for (int i = t; i < 16384; i += NTHREADS) Wl[(i >> 6) * 72 + (i & 63)] = ws[i];
  __syncthreads();
  int wv = t >> 6, lane = t & 63;
  int m = lane & 15, quad = lane >> 4;
  long m0 = (long)blockIdx.x * 64;
  int n0 = wv * 64;
  f4_t zero4 = {0.f, 0.f, 0.f, 0.f};
  f4_t acc[4][4];
#pragma unroll
  for (int mt = 0; mt < 4; mt++)
#pragma unroll
    for (int nt = 0; nt < 4; nt++) acc[mt][nt] = zero4;
  const unsigned short* sp = (const unsigned short*)seq;
#pragma unroll
  for (int ch = 0; ch < 2; ch++) {
    int kof = ch * 32 + quad * 8;
    bs8_t a0 = *(const bs8_t*)(sp + (m0 + 0 * 16 + m) * 64 + kof);
    bs8_t a1 = *(const bs8_t*)(sp + (m0 + 1 * 16 + m) * 64 + kof);
    bs8_t a2 = *(const bs8_t*)(sp + (m0 + 2 * 16 + m) * 64 + kof);
    bs8_t a3 = *(const bs8_t*)(sp + (m0 + 3 * 16 + m) * 64 + kof);
#pragma unroll
    for (int nt = 0; nt < 4; nt++) {
      bs8_t b = *(const bs8_t*)&Wl[(n0 + nt * 16 + m) * 72 + kof];
      acc[0][nt] = __builtin_amdgcn_mfma_f32_16x16x32_bf16(a0, b, acc[0][nt], 0, 0, 0);
      acc[1][nt] = __builtin_amdgcn_mfma_f32_16x16x32_bf16(a1, b, acc[1][nt], 0, 0, 0);
      acc[2][nt] = __builtin_amdgcn_mfma_f32_16x16x32_bf16(a2, b, acc[2][nt], 0, 0, 0);
      acc[3][nt] = __builtin_amdgcn_mfma_f32_16x16x32_bf16(a3, b, acc[3][nt], 0, 0, 0);
    }
  }
  __hip_bfloat16* obuf = (n0 < 128) ? x_in : zg;     // wave-uniform
  int cbase = (n0 < 128) ? n0 : (n0 - 128);
#pragma unroll
  for (int mt = 0; mt < 4; mt++)
#pragma unroll
    for (int nt = 0; nt < 4; nt++) {
      int col = cbase + nt * 16 + m;
#pragma unroll
      for (int rg = 0; rg < 4; rg++) {
        long row = m0 + mt * 16 + quad * 4 + rg;
        obuf[row * 128 + col] = f2bf(acc[mt][nt][rg]);
      }
    }
}

// ---------------- causal depthwise conv1d, in place, full ----------------
__global__ __launch_bounds__(NTHREADS) void k_conv1d_ip(__hip_bfloat16* xio,
                                                        const void* __restrict__ wb,
                                                        const void* __restrict__ bb,
                                                        const int* __restrict__ flagp) {
  int f = *flagp;
  int gid = blockIdx.x * NTHREADS + threadIdx.x;  // < 524,288
  int d = gid & 127, nl = gid >> 7;               // nl < 4096
  float w0 = ldf(wb, d * 4 + 0, f), w1 = ldf(wb, d * 4 + 1, f);
  float w2 = ldf(wb, d * 4 + 2, f), w3 = ldf(wb, d * 4 + 3, f);
  float bias = ldf(bb, d, f);
  float h0 = 0.f, h1 = 0.f, h2 = 0.f;
  size_t off = (size_t)nl * 128 + d;
  const size_t stride = 4096u * 128u;
  for (int z = 0; z < 32; z++) {
    float xv = bf2f(xio[off]);
    float a = bias;
    a = fmaf(h0, w0, a);
    a = fmaf(h1, w1, a);
    a = fmaf(h2, w2, a);
    a = fmaf(xv, w3, a);
    xio[off] = f2bf(a * sigm(a));
    h0 = h1; h1 = h2; h2 = xv;
    off += stride;
  }
}

// ---------------- x_proj, full ----------------
__global__ __launch_bounds__(NTHREADS) void k_xproj(const __hip_bfloat16* __restrict__ A,
                                                    const void* __restrict__ Wb,
                                                    __hip_bfloat16* __restrict__ out,
                                                    const int* __restrict__ flagp) {
  __shared__ float Wt[128 * 41];
  int f = *flagp;
  int t = threadIdx.x;
  for (int i = t; i < 36 * 128; i += NTHREADS) {
    int j = i >> 7, k = i & 127;
    Wt[k * 41 + j] = ldf(Wb, i, f);
  }
  __syncthreads();
  int lane = t & 63, wv = t >> 6;
  int jc = lane < 36 ? lane : 0;
  long m0 = (long)blockIdx.x * 32 + wv * 8;
  float acc[8];
#pragma unroll
  for (int r = 0; r < 8; r++) acc[r] = 0.f;
#pragma unroll
  for (int q = 0; q < 16; q++) {
    float w0 = Wt[(q * 8 + 0) * 41 + jc];
    float w1 = Wt[(q * 8 + 1) * 41 + jc];
    float w2 = Wt[(q * 8 + 2) * 41 + jc];
    float w3 = Wt[(q * 8 + 3) * 41 + jc];
    float w4 = Wt[(q * 8 + 4) * 41 + jc];
    float w5 = Wt[(q * 8 + 5) * 41 + jc];
    float w6 = Wt[(q * 8 + 6) * 41 + jc];
    float w7 = Wt[(q * 8 + 7) * 41 + jc];
#pragma unroll
    for (int r = 0; r < 8; r++) {
      uint4 u = *reinterpret_cast<const uint4*>(A + (size_t)(m0 + r) * 128 + q * 8);
      float a = acc[r];
      a = fmaf(b2f_lo(u.x), w0, a);
      a = fmaf(b2f_hi(u.x), w1, a);
      a = fmaf(b2f_lo(u.y), w2, a);
      a = fmaf(b2f_hi(u.y), w3, a);
      a = fmaf(b2f_lo(u.z), w4, a);
      a = fmaf(b2f_hi(u.z), w5, a);
      a = fmaf(b2f_lo(u.w), w6, a);
      a = fmaf(b2f_hi(u.w), w7, a);
      acc[r] = a;
    }
  }
  if (lane < 36) {
#pragma unroll
    for (int r = 0; r < 8; r++) out[(size_t)(m0 + r) * 36 + lane] = f2bf(acc[r]);
  }
}

// ---------------- selective scan, full ----------------
__global__ __launch_bounds__(NTHREADS) void k_scan(const __hip_bfloat16* __restrict__ xdbl,
                                                   __hip_bfloat16* uy,
                                                   const __hip_bfloat16* __restrict__ zg,
                                                   const void* __restrict__ dtw,
                                                   const void* __restrict__ dtb,
                                                   const void* __restrict__ Alog,
                                                   const void* __restrict__ Dp,
                                                   const int* __restrict__ flagp) {
  int f = *flagp;
  int gid = blockIdx.x * NTHREADS + threadIdx.x;  // < 524,288
  int d = gid & 127, n = gid >> 7;                // n < 4096
  float A[16];
#pragma unroll
  for (int s = 0; s < 16; s++) A[s] = -__expf(fminf(ldf(Alog, d * 16 + s, f), 60.f));
  float W0 = ldf(dtw, d * 4 + 0, f), W1 = ldf(dtw, d * 4 + 1, f);
  float W2 = ldf(dtw, d * 4 + 2, f), W3 = ldf(dtw, d * 4 + 3, f);
  float bias = ldf(dtb, d, f);
  float Dv = ldf(Dp, d, f);
  float st[16];
#pragma unroll
  for (int s = 0; s < 16; s++) st[s] = 0.f;
  for (int z = 0; z < 32; z++) {
    size_t r = (size_t)(z << 12) | n;
    const __hip_bfloat16* bp = xdbl + r * 36;
    float v = bias;
    v = fmaf(bf2f(bp[0]), W0, v);
    v = fmaf(bf2f(bp[1]), W1, v);
    v = fmaf(bf2f(bp[2]), W2, v);
    v = fmaf(bf2f(bp[3]), W3, v);
    float dtv = v > 20.f ? v : log1pf(__expf(v));
    dtv = fminf(fmaxf(dtv, 0.f), 60.f);
    float u = sane(bf2f(uy[r * 128 + d]));
    float zv = sane(bf2f(zg[r * 128 + d]));
    float du = dtv * u;
    float y = 0.f;
#pragma unroll
    for (int s = 0; s < 16; s++) {
      float Bv = bf2f(bp[4 + s]);
      float Cv = bf2f(bp[20 + s]);
      st[s] = fmaf(__expf(dtv * A[s]), st[s], du * Bv);
      y = fmaf(st[s], Cv, y);
    }
    y = sane((y + Dv * u) * (zv * sigm(zv)));
    uy[r * 128 + d] = f2bf(y);
  }
}

// ---------------- W_comb = proj_w @ out_proj_w -> bf16 [o][d] ----------------
__global__ void k_wcomb(const void* __restrict__ pw, const void* __restrict__ opw,
                        __hip_bfloat16* __restrict__ wc, const int* __restrict__ flagp) {
  int f = *flagp;
  int gid = blockIdx.x * NTHREADS + threadIdx.x;  // 8192
  int d = gid & 127, o = gid >> 7;
  float a = 0.f;
#pragma unroll
  for (int j = 0; j < 64; j++) a = fmaf(ldf(pw, o * 64 + j, f), ldf(opw, j * 128 + d, f), a);
  wc[(size_t)o * 128 + d] = f2bf(a);
}

// ---------------- out_proj+proj MFMA: y(131072,128) x Wc^T(128,64) + bias -> s2 ----------------
__global__ __launch_bounds__(NTHREADS) void k_outproj_mfma(const __hip_bfloat16* __restrict__ A,
                                                           const __hip_bfloat16* __restrict__ Wcb,
                                                           const void* __restrict__ bias,
                                                           __hip_bfloat16* __restrict__ out,
                                                           const int* __restrict__ flagp) {
  __shared__ unsigned short Wl[64 * 136];
  __shared__ float bl[64];
  int f = *flagp;
  int t = threadIdx.x;
  const unsigned short* ws = (const unsigned short*)Wcb;
  for (int i = t; i < 8192; i += NTHREADS) Wl[(i >> 7) * 136 + (i & 127)] = ws[i];
  if (t < 64) bl[t] = ldf(bias, t, f);
  __syncthreads();
  int wv = t >> 6, lane = t & 63;
  int m = lane & 15, quad = lane >> 4;
  long m0 = (long)blockIdx.x * 256 + wv * 64;
  f4_t zero4 = {0.f, 0.f, 0.f, 0.f};
  f4_t acc[4][4];
#pragma unroll
  for (int mt = 0; mt < 4; mt++)
#pragma unroll
    for (int nt = 0; nt < 4; nt++) acc[mt][nt] = zero4;
  const unsigned short* ap = (const unsigned short*)A;
#pragma unroll
  for (int ch = 0; ch < 4; ch++) {
    int kof = ch * 32 + quad * 8;
    bs8_t a0 = *(const bs8_t*)(ap + (m0 + 0 * 16 + m) * 128 + kof);
    bs8_t a1 = *(const bs8_t*)(ap + (m0 + 1 * 16 + m) * 128 + kof);
    bs8_t a2 = *(const bs8_t*)(ap + (m0 + 2 * 16 + m) * 128 + kof);
    bs8_t a3 = *(const bs8_t*)(ap + (m0 + 3 * 16 + m) * 128 + kof);
#pragma unroll
    for (int nt = 0; nt < 4; nt++) {
      bs8_t b = *(const bs8_t*)&Wl[(nt * 16 + m) * 136 + kof];
      acc[0][nt] = __builtin_amdgcn_mfma_f32_16x16x32_bf16(a0, b, acc[0][nt], 0, 0, 0);
      acc[1][nt] = __builtin_amdgcn_mfma_f32_16x16x32_bf16(a1, b, acc[1][nt], 0, 0, 0);
      acc[2][nt] = __builtin_amdgcn_mfma_f32_16x16x32_bf16(a2, b, acc[2][nt], 0, 0, 0);
      acc[3][nt] = __builtin_amdgcn_mfma_f32_16x16x32_bf16(a3, b, acc[3][nt], 0, 0, 0);
    }
  }
#pragma unroll
  for (int mt = 0; mt < 4; mt++)
#pragma unroll
    for (int nt = 0; nt < 4; nt++) {
      int co = nt * 16 + m;
#pragma unroll
      for (int rg = 0; rg < 4; rg++) {
        long row = m0 + mt * 16 + quad * 4 + rg;
        out[row * 64 + co] = f2bf(sane(acc[mt][nt][rg] + bl[co]));
      }
    }
}

// ---------------- pn stats ----------------
__global__ __launch_bounds__(NTHREADS) void k_pnstats2(const __hip_bfloat16* __restrict__ s2,
                                                       float* __restrict__ acc) {
  __shared__ float rs[64], rq[64];
  int t = threadIdx.x;
  int c = t & 63;
  int sub = t >> 6;
  float s = 0.f, q = 0.f;
  size_t r0 = (size_t)blockIdx.x * 2048 + sub;
  for (int i = 0; i < 512; i++) {
    float v = sane(bf2f(s2[(r0 + (size_t)i * 4) * 64 + c]));
    s += v;
    q += v * v;
  }
  if (sub == 0) { rs[c] = 0.f; rq[c] = 0.f; }
  __syncthreads();
  for (int w = 0; w < 4; w++) {
    if (sub == w) { rs[c] += s; rq[c] += q; }
    __syncthreads();
  }
  if (t < 64) {
    atomicAdd(&acc[t], rs[t]);
    atomicAdd(&acc[64 + t], rq[t]);
  }
}

// ---------------- final ----------------
__global__ __launch_bounds__(NTHREADS) void k_final(const __hip_bfloat16* __restrict__ s2,
                                                    void* __restrict__ io,
                                                    const float* __restrict__ ss,
                                                    const int* __restrict__ flagp) {
  __shared__ float tile[64 * 65];
  __shared__ float sc[64], sh[64];
  int f = *flagp;
  int t = threadIdx.x;
  if (t < 64) {
    sc[t] = ss[t];
    sh[t] = ss[64 + t];
  }
  int z = blockIdx.x >> 6, n0 = (blockIdx.x & 63) << 6;
  size_t base = ((size_t)z * 4096 + n0) * 64;
  __syncthreads();
#pragma unroll
  for (int jj = 0; jj < 16; jj++) {
    int id = t + jj * NTHREADS;
    int i = id >> 6, c = id & 63;
    float v = sane(bf2f(s2[base + id]));
    tile[i * 65 + c] = sc[c] * v + sh[c];
  }
  __syncthreads();
#pragma unroll
  for (int jj = 0; jj < 16; jj++) {
    int id = t + jj * NTHREADS;
    int c = id >> 6, nl = id & 63;
    size_t off = (size_t)c * 131072 + (size_t)z * 4096 + n0 + nl;
    if (f) {
      float* o = (float*)io;
      o[off] = sane(o[off] + tile[nl * 65 + c]);
    } else {
      __hip_bfloat16* o = (__hip_bfloat16*)io;
      o[off] = f2bf(sane(bf2f(o[off]) + tile[nl * 65 + c]));
    }
  }
}

// ---------------- launch ----------------
extern "C" void kernel_launch(void* const* d_in, const int* in_sizes, int n_in,
                              void* d_out, int out_size, void* d_ws, size_t ws_size,
                              hipStream_t stream) {
  (void)in_sizes; (void)n_in; (void)out_size; (void)ws_size;
  const void* x        = d_in[0];
  const void* c1_w     = d_in[1];
  const void* in1_g    = d_in[2];
  const void* in1_b    = d_in[3];
  const void* c2_w     = d_in[4];
  const void* in2_g    = d_in[5];
  const void* in2_b    = d_in[6];
  const void* dw_w     = d_in[7];
  const void* pw_w     = d_in[8];
  const void* inr_g    = d_in[9];
  const void* inr_b    = d_in[10];
  const void* ln_g     = d_in[11];
  const void* ln_b     = d_in[12];
  const void* in_proj_w= d_in[13];
  const void* conv1d_w = d_in[14];
  const void* conv1d_b = d_in[15];
  const void* x_proj_w = d_in[16];
  const void* dt_proj_w= d_in[17];
  const void* dt_proj_b= d_in[18];
  const void* A_log    = d_in[19];
  const void* D_p      = d_in[20];
  const void* out_proj_w=d_in[21];
  const void* proj_w   = d_in[22];
  const void* proj_b   = d_in[23];
  const void* pn_g     = d_in[24];
  const void* pn_b     = d_in[25];

  char* wb = (char*)d_ws;
  // Byte layout, TOTAL ~= 85.3 MB (< 90.3 MB proven mapped in R7).
  // R0 [0, 33,554,432): P1(9.5M) -> P2(19.5M) -> zg(33.5M) -> s2(16.8M)
  __hip_bfloat16* P1   = (__hip_bfloat16*)wb;
  __hip_bfloat16* P2   = (__hip_bfloat16*)wb;
  __hip_bfloat16* zgb  = (__hip_bfloat16*)wb;
  __hip_bfloat16* s2   = (__hip_bfloat16*)wb;
  // R1 [33,554,432, 67,108,864): c1raw(17.3M) -> c2raw(17.8M) | pre2(16.8M) -> x_in(33.5M)
  __hip_bfloat16* c1raw = (__hip_bfloat16*)(wb + 33554432);
  __hip_bfloat16* c2raw = (__hip_bfloat16*)(wb + 33554432);
  __hip_bfloat16* pre2  = (__hip_bfloat16*)(wb + 33554432);   // after c2raw dead
  __hip_bfloat16* x_in  = (__hip_bfloat16*)(wb + 33554432);   // after pre2+hcl dead
  // hcl [51,380,224, 68,157,440)  (adjacent to c2raw end)
  __hip_bfloat16* hcl   = (__hip_bfloat16*)(wb + 51380224);
  // seq [68,157,440, 84,934,656); xdbl aliases seq after inproj
  __hip_bfloat16* seq   = (__hip_bfloat16*)(wb + 68157440);
  __hip_bfloat16* xdbl  = (__hip_bfloat16*)(wb + 68157440);
  // weights [84,934,656 ...)
  __hip_bfloat16* W1b   = (__hip_bfloat16*)(wb + 84934656);             // 73,728 B
  __hip_bfloat16* W2b   = (__hip_bfloat16*)(wb + 85008384);             // 147,456 B
  __hip_bfloat16* inwb  = (__hip_bfloat16*)(wb + 85155840);             // 32,768 B
  __hip_bfloat16* wcombb= (__hip_bfloat16*)(wb + 85188608);             // 16,384 B
  __hip_bfloat16* pwbb  = (__hip_bfloat16*)(wb + 85204992);             // 8,192 B
  float*          fst   = (float*)(wb + 85213184);

  float* acc_in1 = fst;
  float* acc_in2 = fst + 128;
  float* acc_inr = fst + 256;
  float* acc_pn  = fst + 384;
  float* ss_in1  = fst + 512;
  float* ss_in2  = fst + 640;
  float* ss_inr  = fst + 768;
  float* ss_pn   = fst + 896;
  int*   flagp   = (int*)(fst + 1024);

  hipMemsetAsync(fst, 0, 512 * sizeof(float), stream);

  k_detect<<<1, NTHREADS, 0, stream>>>(x, flagp);
  k_pad1<<<34 * 66, NTHREADS, 0, stream>>>(x, P1, flagp);
  k_prepw<<<144, NTHREADS, 0, stream>>>(c1_w, W1b, 32, flagp);
  k_prepw<<<288, NTHREADS, 0, stream>>>(c2_w, W2b, 64, flagp);
  k_prepcvt<<<64, NTHREADS, 0, stream>>>(in_proj_w, inwb, 16384, flagp);
  k_prepcvt<<<16, NTHREADS, 0, stream>>>(pw_w, pwbb, 4096, flagp);
  k_wcomb<<<32, NTHREADS, 0, stream>>>(proj_w, out_proj_w, wcombb, flagp);

  k_gemm_conv<32, 40><<<33 * 16, NTHREADS, 0, stream>>>(P1, W1b, c1raw);
  k_stats_cl<<<256, NTHREADS, 0, stream>>>(c1raw, acc_in1, 528);
  k_finalize<<<1, 64, 0, stream>>>(acc_in1, in1_g, in1_b, ss_in1, 1.0f / 135168.0f, flagp);
  k_normpad<<<35 * 66, NTHREADS, 0, stream>>>(c1raw, ss_in1, P2);

  k_gemm_conv<64, 88><<<34 * 16, NTHREADS, 0, stream>>>(P2, W2b, c2raw);
  k_stats_cl<<<256, NTHREADS, 0, stream>>>(c2raw, acc_in2, 544);
  k_finalize<<<1, 64, 0, stream>>>(acc_in2, in2_g, in2_b, ss_in2, 1.0f / 139264.0f, flagp);
  k_hslice_cl<<<2048, NTHREADS, 0, stream>>>(c2raw, ss_in2, hcl, d_out, flagp);

  k_dwpw_mfma<<<2048, NTHREADS, 0, stream>>>(hcl, dw_w, pwbb, pre2, acc_inr, flagp);
  k_finalize<<<1, 64, 0, stream>>>(acc_inr, inr_g, inr_b, ss_inr, 1.0f / 131072.0f, flagp);
  k_x2ln_cl<<<512, NTHREADS, 0, stream>>>(hcl, pre2, ss_inr, ln_g, ln_b, seq, flagp);

  k_inproj_mfma<<<2048, NTHREADS, 0, stream>>>(seq, inwb, x_in, zgb);
  k_conv1d_ip<<<2048, NTHREADS, 0, stream>>>(x_in, conv1d_w, conv1d_b, flagp);
  k_xproj<<<4096, NTHREADS, 0, stream>>>(x_in, x_proj_w, xdbl, flagp);
  k_scan<<<2048, NTHREADS, 0, stream>>>(xdbl, x_in, zgb, dt_proj_w, dt_proj_b, A_log, D_p, flagp);
  k_outproj_mfma<<<512, NTHREADS, 0, stream>>>(x_in, wcombb, proj_b, s2, flagp);

  k_pnstats2<<<64, NTHREADS, 0, stream>>>(s2, acc_pn);
  k_finalize<<<1, 64, 0, stream>>>(acc_pn, pn_g, pn_b, ss_pn, 1.0f / 131072.0f, flagp);
  k_final<<<2048, NTHREADS, 0, stream>>>(s2, d_out, ss_pn, flagp);
}

// Round 9
// 702.722 us; speedup vs baseline: 8.8577x; 1.2362x over previous
//
#include <hip/hip_runtime.h>
#include <hip/hip_bf16.h>

// Hybrid decoder block, MFMA everywhere GEMM-shaped, channels-last internals.
// row convention: r = z*4096 + n, n = y*64+x.
#define NTHREADS 256

typedef __attribute__((ext_vector_type(8))) short bs8_t;   // 8 bf16 (4 VGPRs)
typedef __attribute__((ext_vector_type(4))) float f4_t;    // 4 fp32 acc

__device__ __forceinline__ float bf2f(__hip_bfloat16 v) { return __bfloat162float(v); }
__device__ __forceinline__ __hip_bfloat16 f2bf(float v) { return __float2bfloat16(v); }
__device__ __forceinline__ float b2f_lo(unsigned int p) { return __uint_as_float(p << 16); }
__device__ __forceinline__ float b2f_hi(unsigned int p) { return __uint_as_float(p & 0xffff0000u); }
__device__ __forceinline__ float sigm(float x) { return 1.f / (1.f + __expf(-x)); }
__device__ __forceinline__ float leaky(float x) { return x > 0.f ? x : 0.01f * x; }
__device__ __forceinline__ float sane(float x) { return fminf(fmaxf(x, -1e9f), 1e9f); }
__device__ __forceinline__ unsigned packbf(float a, float b) {
  union { __hip_bfloat16 h[2]; unsigned u; } cv;
  cv.h[0] = f2bf(a); cv.h[1] = f2bf(b);
  return cv.u;
}
__device__ __forceinline__ float ldf(const void* p, long i, int f) {
  return f ? ((const float*)p)[i] : bf2f(((const __hip_bfloat16*)p)[i]);
}

// ---------------- dtype detector ----------------
__global__ void k_detect(const void* xp, int* flag) {
  __shared__ int cnt[NTHREADS];
  const __hip_bfloat16* h = (const __hip_bfloat16*)xp;
  int t = threadIdx.x;
  int c = 0;
  for (int j = 0; j < 8; j++) {
    float v = fabsf(bf2f(h[(t * 8 + j) * 2]));
    if (v > 1e-12f && v < 1e12f) c++;
  }
  cnt[t] = c;
  __syncthreads();
  for (int s = 128; s > 0; s >>= 1) {
    if (t < s) cnt[t] += cnt[t + s];
    __syncthreads();
  }
  if (t == 0) *flag = (cnt[0] > 1433) ? 0 : 1;
}

// generic converter: out[i] = bf16(in[i])
__global__ void k_prepcvt(const void* __restrict__ in, __hip_bfloat16* __restrict__ out,
                          int n, const int* __restrict__ flagp) {
  int f = *flagp;
  int gid = blockIdx.x * NTHREADS + threadIdx.x;
  if (gid < n) out[gid] = f2bf(ldf(in, gid, f));
}

// ---------------- pad1: x (ci-first) -> P1[z'(34)][y'(66)][x'(66)][32] bf16 ----------------
__global__ __launch_bounds__(NTHREADS) void k_pad1(const void* __restrict__ x,
                                                   __hip_bfloat16* __restrict__ P1,
                                                   const int* __restrict__ flagp) {
  __shared__ float tile[64 * 33];
  int f = *flagp;
  int zp = blockIdx.x / 66, yp = blockIdx.x % 66;
  long rowbase = ((long)zp * 66 + yp) * 66 * 32;
  int t = threadIdx.x;
  if (zp == 0 || zp == 33 || yp == 0 || yp == 65) {
    for (int i = t; i < 2112; i += NTHREADS) P1[rowbase + i] = f2bf(0.f);
    return;
  }
  int z = zp - 1, y = yp - 1;
#pragma unroll
  for (int j = 0; j < 8; j++) {
    int idx = t + j * NTHREADS;
    int ci = idx >> 6, xx = idx & 63;
    tile[xx * 33 + ci] = ldf(x, (long)(ci * 32 + z) * 4096 + y * 64 + xx, f);
  }
  __syncthreads();
#pragma unroll
  for (int j = 0; j < 8; j++) {
    int idx = t + j * NTHREADS;
    int xx = idx >> 5, ci = idx & 31;
    P1[rowbase + (xx + 1) * 32 + ci] = f2bf(tile[xx * 33 + ci]);
  }
  if (t < 32) P1[rowbase + t] = f2bf(0.f);
  else if (t < 64) P1[rowbase + 65 * 32 + (t - 32)] = f2bf(0.f);
}

// ---------------- weight reorg: cw (co,ci,2,3,3) -> W[s][co][ci] bf16 ----------------
__global__ void k_prepw(const void* __restrict__ cw, __hip_bfloat16* __restrict__ W,
                        int CI, const int* __restrict__ flagp) {
  int f = *flagp;
  int gid = blockIdx.x * NTHREADS + threadIdx.x;
  int s = gid / (64 * CI);
  int rem = gid % (64 * CI);
  int co = rem / CI, ci = rem % CI;
  W[gid] = f2bf(ldf(cw, (long)(co * CI + ci) * 18 + s, f));
}

// ---------------- MFMA implicit-GEMM conv ----------------
template <int CI, int CIP>
__global__ __launch_bounds__(NTHREADS) void k_gemm_conv(const __hip_bfloat16* __restrict__ Pb,
                                                        const __hip_bfloat16* __restrict__ Wb,
                                                        __hip_bfloat16* __restrict__ out) {
  __shared__ unsigned short Wl[3 * 64 * CIP];
  const unsigned short* P = (const unsigned short*)Pb;
  const unsigned short* W = (const unsigned short*)Wb;
  int t = threadIdx.x;
  int wv = t >> 6, lane = t & 63;
  int m = lane & 15, quad = lane >> 4;
  int zo = blockIdx.x >> 4;
  int y  = ((blockIdx.x & 15) << 2) + wv;
  f4_t zero4 = {0.f, 0.f, 0.f, 0.f};
  f4_t acc[4][4];
#pragma unroll
  for (int mt = 0; mt < 4; mt++)
#pragma unroll
    for (int nt = 0; nt < 4; nt++) acc[mt][nt] = zero4;

  for (int kz = 0; kz < 2; kz++) {
    for (int ky = 0; ky < 3; ky++) {
      __syncthreads();
      int s0 = (kz * 3 + ky) * 3;
      const unsigned short* wsrc = W + (long)s0 * 64 * CI;
      for (int i = t; i < 3 * 64 * CI; i += NTHREADS) {
        int kx = i / (64 * CI), rem = i % (64 * CI);
        int co = rem / CI, ci = rem % CI;
        Wl[(kx * 64 + co) * CIP + ci] = wsrc[i];
      }
      __syncthreads();
      int pz = zo + kz, py = y + ky;
      const unsigned short* prow = P + ((long)(pz * 66 + py) * 66) * CI;
#pragma unroll
      for (int kx = 0; kx < 3; kx++) {
#pragma unroll
        for (int ch = 0; ch < CI / 32; ch++) {
          int kof = kx * CI + ch * 32 + quad * 8;
          bs8_t a0 = *(const bs8_t*)(prow + (0 * 16 + m) * CI + kof);
          bs8_t a1 = *(const bs8_t*)(prow + (1 * 16 + m) * CI + kof);
          bs8_t a2 = *(const bs8_t*)(prow + (2 * 16 + m) * CI + kof);
          bs8_t a3 = *(const bs8_t*)(prow + (3 * 16 + m) * CI + kof);
#pragma unroll
          for (int nt = 0; nt < 4; nt++) {
            bs8_t b = *(const bs8_t*)&Wl[(kx * 64 + nt * 16 + m) * CIP + ch * 32 + quad * 8];
            acc[0][nt] = __builtin_amdgcn_mfma_f32_16x16x32_bf16(a0, b, acc[0][nt], 0, 0, 0);
            acc[1][nt] = __builtin_amdgcn_mfma_f32_16x16x32_bf16(a1, b, acc[1][nt], 0, 0, 0);
            acc[2][nt] = __builtin_amdgcn_mfma_f32_16x16x32_bf16(a2, b, acc[2][nt], 0, 0, 0);
            acc[3][nt] = __builtin_amdgcn_mfma_f32_16x16x32_bf16(a3, b, acc[3][nt], 0, 0, 0);
          }
        }
      }
    }
  }
  long obase = ((long)(zo * 64 + y) * 64) * 64;
#pragma unroll
  for (int mt = 0; mt < 4; mt++)
#pragma unroll
    for (int nt = 0; nt < 4; nt++) {
      int co = nt * 16 + m;
#pragma unroll
      for (int rg = 0; rg < 4; rg++) {
        int xx = mt * 16 + quad * 4 + rg;
        out[obase + xx * 64 + co] = f2bf(acc[mt][nt][rg]);
      }
    }
}

// ---------------- per-channel stats over channels-last [rows][64] bf16 ----------------
__global__ __launch_bounds__(NTHREADS) void k_stats_cl(const __hip_bfloat16* __restrict__ in,
                                                       float* __restrict__ acc, int rpb) {
  __shared__ float rs[64], rq[64];
  int t = threadIdx.x;
  int c = t & 63, sub = t >> 6;
  float s = 0.f, q = 0.f;
  long r0 = (long)blockIdx.x * rpb + sub;
  for (int i = 0; i < rpb / 4; i++) {
    float v = bf2f(in[(r0 + (long)i * 4) * 64 + c]);
    s += v;
    q += v * v;
  }
  if (sub == 0) { rs[c] = 0.f; rq[c] = 0.f; }
  __syncthreads();
  for (int w = 0; w < 4; w++) {
    if (sub == w) { rs[c] += s; rq[c] += q; }
    __syncthreads();
  }
  if (t < 64) {
    atomicAdd(&acc[t], rs[t]);
    atomicAdd(&acc[64 + t], rq[t]);
  }
}

__global__ void k_finalize(const float* __restrict__ acc, const void* __restrict__ g,
                           const void* __restrict__ b, float* __restrict__ ss, float invN,
                           const int* __restrict__ flagp) {
  int f = *flagp;
  int t = threadIdx.x;  // 64
  float mean = acc[t] * invN;
  float var  = acc[64 + t] * invN - mean * mean;
  float rstd = rsqrtf(fmaxf(var, 0.f) + 1e-5f);
  float sc   = ldf(g, t, f) * rstd;
  ss[t]      = sc;
  ss[64 + t] = ldf(b, t, f) - mean * sc;
}

// ---------------- normpad: c1raw -> norm+leaky -> P2[35][66][66][64] ----------------
__global__ __launch_bounds__(NTHREADS) void k_normpad(const __hip_bfloat16* __restrict__ in,
                                                      const float* __restrict__ ss,
                                                      __hip_bfloat16* __restrict__ P2) {
  int zp = blockIdx.x / 66, yp = blockIdx.x % 66;
  long rowbase = ((long)zp * 66 + yp) * 66 * 64;
  int t = threadIdx.x;
  if (zp == 0 || zp == 34 || yp == 0 || yp == 65) {
    for (int i = t; i < 4224; i += NTHREADS) P2[rowbase + i] = f2bf(0.f);
    return;
  }
  int z = zp - 1, y = yp - 1;
#pragma unroll
  for (int j = 0; j < 16; j++) {
    int idx = t + j * NTHREADS;
    int xx = idx >> 6, co = idx & 63;
    float v = bf2f(in[((long)(z * 64 + y) * 64 + xx) * 64 + co]) * ss[co] + ss[64 + co];
    P2[rowbase + (xx + 1) * 64 + co] = f2bf(leaky(v));
  }
  if (t < 64) P2[rowbase + t] = f2bf(0.f);
  else if (t < 128) P2[rowbase + 65 * 64 + (t - 64)] = f2bf(0.f);
}

// ---------------- hslice: c2raw -> norm+leaky -> hcl + residual d_out[c][r] ----------------
__global__ __launch_bounds__(NTHREADS) void k_hslice_cl(const __hip_bfloat16* __restrict__ in,
                                                        const float* __restrict__ ss,
                                                        __hip_bfloat16* __restrict__ hcl,
                                                        void* __restrict__ resid,
                                                        const int* __restrict__ flagp) {
  __shared__ float tile[64 * 65];
  int f = *flagp;
  int z = blockIdx.x >> 6, y = blockIdx.x & 63;
  long r0 = (long)z * 4096 + y * 64;
  int t = threadIdx.x;
#pragma unroll
  for (int j = 0; j < 16; j++) {
    int idx = t + j * NTHREADS;
    int xx = idx >> 6, co = idx & 63;
    float v = leaky(bf2f(in[(r0 + xx) * 64 + co]) * ss[co] + ss[64 + co]);
    hcl[(r0 + xx) * 64 + co] = f2bf(v);
    tile[xx * 65 + co] = v;
  }
  __syncthreads();
#pragma unroll
  for (int j = 0; j < 16; j++) {
    int idx = t + j * NTHREADS;
    int co = idx >> 6, xx = idx & 63;
    long off = (long)co * 131072 + r0 + xx;
    if (f) ((float*)resid)[off] = tile[xx * 65 + co];
    else   ((__hip_bfloat16*)resid)[off] = f2bf(tile[xx * 65 + co]);
  }
}

// ---------------- dw3x3 + pw1x1 (MFMA pointwise) + inr stats ----------------
__global__ __launch_bounds__(NTHREADS) void k_dwpw_mfma(const __hip_bfloat16* __restrict__ hcl,
                                                        const void* __restrict__ dwb,
                                                        const __hip_bfloat16* __restrict__ pwbb,
                                                        __hip_bfloat16* __restrict__ out,
                                                        float* __restrict__ acc,
                                                        const int* __restrict__ flagp) {
  __shared__ unsigned short hl[3 * 64 * 64];
  __shared__ unsigned short dwt[64 * 72];
  __shared__ unsigned short pwl[64 * 72];
  __shared__ float dwl[576];
  __shared__ float sred[256], qred[256];
  int f = *flagp;
  int t = threadIdx.x;
  int z = blockIdx.x >> 6, y = blockIdx.x & 63;
  for (int i = t; i < 576; i += NTHREADS) dwl[i] = ldf(dwb, i, f);
  {
    const unsigned short* ps = (const unsigned short*)pwbb;
    for (int i = t; i < 4096; i += NTHREADS) pwl[(i >> 6) * 72 + (i & 63)] = ps[i];
  }
  const unsigned short* hsrc = (const unsigned short*)hcl;
  for (int i = t; i < 12288; i += NTHREADS) {
    int dy = i / 4096, rem = i & 4095;
    int ry = y - 1 + dy;
    hl[i] = ((unsigned)ry < 64u) ? hsrc[((long)z * 4096 + ry * 64) * 64 + rem] : (unsigned short)0;
  }
  __syncthreads();
  const unsigned* hl32 = (const unsigned*)hl;
  unsigned* dwt32 = (unsigned*)dwt;
#pragma unroll
  for (int j = 0; j < 8; j++) {
    int idx = t + j * NTHREADS;
    int xx = idx >> 5, cp = idx & 31;
    float a0 = 0.f, a1 = 0.f;
#pragma unroll
    for (int dy = 0; dy < 3; dy++)
#pragma unroll
      for (int dx = 0; dx < 3; dx++) {
        int xv = xx - 1 + dx;
        if ((unsigned)xv < 64u) {
          unsigned hv = hl32[(dy * 64 + xv) * 32 + cp];
          a0 = fmaf(b2f_lo(hv), dwl[(cp * 2) * 9 + dy * 3 + dx], a0);
          a1 = fmaf(b2f_hi(hv), dwl[(cp * 2 + 1) * 9 + dy * 3 + dx], a1);
        }
      }
    dwt32[xx * 36 + cp] = packbf(a0, a1);
  }
  __syncthreads();
  int wv = t >> 6, lane = t & 63;
  int m = lane & 15, quad = lane >> 4;
  f4_t zero4 = {0.f, 0.f, 0.f, 0.f};
  f4_t acc4[4];
#pragma unroll
  for (int nt = 0; nt < 4; nt++) acc4[nt] = zero4;
#pragma unroll
  for (int ch = 0; ch < 2; ch++) {
    bs8_t a = *(const bs8_t*)&dwt[(wv * 16 + m) * 72 + ch * 32 + quad * 8];
#pragma unroll
    for (int nt = 0; nt < 4; nt++) {
      bs8_t b = *(const bs8_t*)&pwl[(nt * 16 + m) * 72 + ch * 32 + quad * 8];
      acc4[nt] = __builtin_amdgcn_mfma_f32_16x16x32_bf16(a, b, acc4[nt], 0, 0, 0);
    }
  }
  long obase = ((long)z * 4096 + y * 64) * 64;
  float psum[4], pq[4];
#pragma unroll
  for (int nt = 0; nt < 4; nt++) {
    float s = 0.f, q = 0.f;
#pragma unroll
    for (int rg = 0; rg < 4; rg++) {
      float v = acc4[nt][rg];
      int xx = wv * 16 + quad * 4 + rg;
      out[obase + xx * 64 + nt * 16 + m] = f2bf(v);
      s += v;
      q += v * v;
    }
    psum[nt] = s;
    pq[nt] = q;
  }
#pragma unroll
  for (int nt = 0; nt < 4; nt++) {
    psum[nt] += __shfl_xor(psum[nt], 16, 64);
    psum[nt] += __shfl_xor(psum[nt], 32, 64);
    pq[nt]   += __shfl_xor(pq[nt], 16, 64);
    pq[nt]   += __shfl_xor(pq[nt], 32, 64);
  }
  if (quad == 0) {
#pragma unroll
    for (int nt = 0; nt < 4; nt++) {
      sred[wv * 64 + nt * 16 + m] = psum[nt];
      qred[wv * 64 + nt * 16 + m] = pq[nt];
    }
  }
  __syncthreads();
  if (t < 64) {
    atomicAdd(&acc[t], sred[t] + sred[64 + t] + sred[128 + t] + sred[192 + t]);
    atomicAdd(&acc[64 + t], qred[t] + qred[64 + t] + qred[128 + t] + qred[192 + t]);
  }
}

// ---------------- x2 = h + silu(norm(pre2)); LayerNorm C=64 -> seq bf16 ----------------
__global__ __launch_bounds__(NTHREADS) void k_x2ln_cl(const __hip_bfloat16* __restrict__ hcl,
                                                      const __hip_bfloat16* __restrict__ p2,
                                                      const float* __restrict__ ssr,
                                                      const void* __restrict__ lng,
                                                      const void* __restrict__ lnb,
                                                      __hip_bfloat16* __restrict__ out,
                                                      const int* __restrict__ flagp) {
  __shared__ float sc[64], sh[64], sg[64], sb[64];
  int f = *flagp;
  int t = threadIdx.x;
  if (t < 64) {
    sc[t] = ssr[t];
    sh[t] = ssr[64 + t];
    sg[t] = ldf(lng, t, f);
    sb[t] = ldf(lnb, t, f);
  }
  __syncthreads();
  long r = (long)blockIdx.x * NTHREADS + t;
  const uint4* hp = (const uint4*)(hcl + r * 64);
  const uint4* pp = (const uint4*)(p2 + r * 64);
  float v[64];
  float s1 = 0.f;
#pragma unroll
  for (int q = 0; q < 8; q++) {
    uint4 hu = hp[q], pu = pp[q];
    float hv[8] = {b2f_lo(hu.x), b2f_hi(hu.x), b2f_lo(hu.y), b2f_hi(hu.y),
                   b2f_lo(hu.z), b2f_hi(hu.z), b2f_lo(hu.w), b2f_hi(hu.w)};
    float pv[8] = {b2f_lo(pu.x), b2f_hi(pu.x), b2f_lo(pu.y), b2f_hi(pu.y),
                   b2f_lo(pu.z), b2f_hi(pu.z), b2f_lo(pu.w), b2f_hi(pu.w)};
#pragma unroll
    for (int i = 0; i < 8; i++) {
      int c = q * 8 + i;
      float pn = sc[c] * pv[i] + sh[c];
      float x2 = hv[i] + pn * sigm(pn);
      v[c] = x2;
      s1 += x2;
    }
  }
  float m = s1 * (1.f / 64.f);
  float s2 = 0.f;
#pragma unroll
  for (int c = 0; c < 64; c++) {
    float d = v[c] - m;
    s2 += d * d;
  }
  float rstd = rsqrtf(s2 * (1.f / 64.f) + 1e-5f);
  uint4* o4 = (uint4*)(out + r * 64);
#pragma unroll
  for (int q = 0; q < 8; q++) {
    int c = q * 8;
    uint4 o;
    o.x = packbf((v[c + 0] - m) * rstd * sg[c + 0] + sb[c + 0],
                 (v[c + 1] - m) * rstd * sg[c + 1] + sb[c + 1]);
    o.y = packbf((v[c + 2] - m) * rstd * sg[c + 2] + sb[c + 2],
                 (v[c + 3] - m) * rstd * sg[c + 3] + sb[c + 3]);
    o.z = packbf((v[c + 4] - m) * rstd * sg[c + 4] + sb[c + 4],
                 (v[c + 5] - m) * rstd * sg[c + 5] + sb[c + 5]);
    o.w = packbf((v[c + 6] - m) * rstd * sg[c + 6] + sb[c + 6],
                 (v[c + 7] - m) * rstd * sg[c + 7] + sb[c + 7]);
    o4[q] = o;
  }
}

// ---------------- in_proj MFMA ----------------
__global__ __launch_bounds__(NTHREADS) void k_inproj_mfma(const __hip_bfloat16* __restrict__ seq,
                                                          const __hip_bfloat16* __restrict__ Wbf,
                                                          __hip_bfloat16* __restrict__ x_in,
                                                          __hip_bfloat16* __restrict__ zg) {
  __shared__ unsigned short Wl[256 * 72];
  const unsigned short* ws = (const unsigned short*)Wbf;
  int t = threadIdx.x;
  for (int i = t; i < 16384; i += NTHREADS) Wl[(i >> 6) * 72 + (i & 63)] = ws[i];
  __syncthreads();
  int wv = t >> 6, lane = t & 63;
  int m = lane & 15, quad = lane >> 4;
  long m0 = (long)blockIdx.x * 64;
  int n0 = wv * 64;
  f4_t zero4 = {0.f, 0.f, 0.f, 0.f};
  f4_t acc[4][4];
#pragma unroll
  for (int mt = 0; mt < 4; mt++)
#pragma unroll
    for (int nt = 0; nt < 4; nt++) acc[mt][nt] = zero4;
  const unsigned short* sp = (const unsigned short*)seq;
#pragma unroll
  for (int ch = 0; ch < 2; ch++) {
    int kof = ch * 32 + quad * 8;
    bs8_t a0 = *(const bs8_t*)(sp + (m0 + 0 * 16 + m) * 64 + kof);
    bs8_t a1 = *(const bs8_t*)(sp + (m0 + 1 * 16 + m) * 64 + kof);
    bs8_t a2 = *(const bs8_t*)(sp + (m0 + 2 * 16 + m) * 64 + kof);
    bs8_t a3 = *(const bs8_t*)(sp + (m0 + 3 * 16 + m) * 64 + kof);
#pragma unroll
    for (int nt = 0; nt < 4; nt++) {
      bs8_t b = *(const bs8_t*)&Wl[(n0 + nt * 16 + m) * 72 + kof];
      acc[0][nt] = __builtin_amdgcn_mfma_f32_16x16x32_bf16(a0, b, acc[0][nt], 0, 0, 0);
      acc[1][nt] = __builtin_amdgcn_mfma_f32_16x16x32_bf16(a1, b, acc[1][nt], 0, 0, 0);
      acc[2][nt] = __builtin_amdgcn_mfma_f32_16x16x32_bf16(a2, b, acc[2][nt], 0, 0, 0);
      acc[3][nt] = __builtin_amdgcn_mfma_f32_16x16x32_bf16(a3, b, acc[3][nt], 0, 0, 0);
    }
  }
  __hip_bfloat16* obuf = (n0 < 128) ? x_in : zg;
  int cbase = (n0 < 128) ? n0 : (n0 - 128);
#pragma unroll
  for (int mt = 0; mt < 4; mt++)
#pragma unroll
    for (int nt = 0; nt < 4; nt++) {
      int col = cbase + nt * 16 + m;
#pragma unroll
      for (int rg = 0; rg < 4; rg++) {
        long row = m0 + mt * 16 + quad * 4 + rg;
        obuf[row * 128 + col] = f2bf(acc[mt][nt][rg]);
      }
    }
}

// ---------------- causal depthwise conv1d, in place ----------------
__global__ __launch_bounds__(NTHREADS) void k_conv1d_ip(__hip_bfloat16* xio,
                                                        const void* __restrict__ wb,
                                                        const void* __restrict__ bb,
                                                        const int* __restrict__ flagp) {
  int f = *flagp;
  int gid = blockIdx.x * NTHREADS + threadIdx.x;
  int d = gid & 127, nl = gid >> 7;
  float w0 = ldf(wb, d * 4 + 0, f), w1 = ldf(wb, d * 4 + 1, f);
  float w2 = ldf(wb, d * 4 + 2, f), w3 = ldf(wb, d * 4 + 3, f);
  float bias = ldf(bb, d, f);
  float h0 = 0.f, h1 = 0.f, h2 = 0.f;
  size_t off = (size_t)nl * 128 + d;
  const size_t stride = 4096u * 128u;
  for (int z = 0; z < 32; z++) {
    float xv = bf2f(xio[off]);
    float a = bias;
    a = fmaf(h0, w0, a);
    a = fmaf(h1, w1, a);
    a = fmaf(h2, w2, a);
    a = fmaf(xv, w3, a);
    xio[off] = f2bf(a * sigm(a));
    h0 = h1; h1 = h2; h2 = xv;
    off += stride;
  }
}

// ---------------- x_proj MFMA: (131072,128) x (36->48 pad,128)^T -> xdbl (131072,36) ----------------
__global__ __launch_bounds__(NTHREADS) void k_xproj_mfma(const __hip_bfloat16* __restrict__ A,
                                                         const __hip_bfloat16* __restrict__ Wbf,
                                                         __hip_bfloat16* __restrict__ out) {
  __shared__ unsigned short Wl[48 * 136];
  const unsigned short* ws = (const unsigned short*)Wbf;   // (36,128) row-major
  int t = threadIdx.x;
  for (int i = t; i < 48 * 128; i += NTHREADS) {
    int j = i >> 7, k = i & 127;
    Wl[j * 136 + k] = (j < 36) ? ws[j * 128 + k] : (unsigned short)0;
  }
  __syncthreads();
  int wv = t >> 6, lane = t & 63;
  int m = lane & 15, quad = lane >> 4;
  long m0 = (long)blockIdx.x * 256 + wv * 64;
  f4_t zero4 = {0.f, 0.f, 0.f, 0.f};
  f4_t acc[4][3];
#pragma unroll
  for (int mt = 0; mt < 4; mt++)
#pragma unroll
    for (int nt = 0; nt < 3; nt++) acc[mt][nt] = zero4;
  const unsigned short* ap = (const unsigned short*)A;
#pragma unroll
  for (int ch = 0; ch < 4; ch++) {
    int kof = ch * 32 + quad * 8;
    bs8_t a0 = *(const bs8_t*)(ap + (m0 + 0 * 16 + m) * 128 + kof);
    bs8_t a1 = *(const bs8_t*)(ap + (m0 + 1 * 16 + m) * 128 + kof);
    bs8_t a2 = *(const bs8_t*)(ap + (m0 + 2 * 16 + m) * 128 + kof);
    bs8_t a3 = *(const bs8_t*)(ap + (m0 + 3 * 16 + m) * 128 + kof);
#pragma unroll
    for (int nt = 0; nt < 3; nt++) {
      bs8_t b = *(const bs8_t*)&Wl[(nt * 16 + m) * 136 + kof];
      acc[0][nt] = __builtin_amdgcn_mfma_f32_16x16x32_bf16(a0, b, acc[0][nt], 0, 0, 0);
      acc[1][nt] = __builtin_amdgcn_mfma_f32_16x16x32_bf16(a1, b, acc[1][nt], 0, 0, 0);
      acc[2][nt] = __builtin_amdgcn_mfma_f32_16x16x32_bf16(a2, b, acc[2][nt], 0, 0, 0);
      acc[3][nt] = __builtin_amdgcn_mfma_f32_16x16x32_bf16(a3, b, acc[3][nt], 0, 0, 0);
    }
  }
#pragma unroll
  for (int mt = 0; mt < 4; mt++)
#pragma unroll
    for (int nt = 0; nt < 3; nt++) {
      int col = nt * 16 + m;
      if (col < 36) {
#pragma unroll
        for (int rg = 0; rg < 4; rg++) {
          long row = m0 + mt * 16 + quad * 4 + rg;
          out[row * 36 + col] = f2bf(acc[mt][nt][rg]);
        }
      }
    }
}

// ---------------- selective scan ----------------
__global__ __launch_bounds__(NTHREADS) void k_scan(const __hip_bfloat16* __restrict__ xdbl,
                                                   __hip_bfloat16* uy,
                                                   const __hip_bfloat16* __restrict__ zg,
                                                   const void* __restrict__ dtw,
                                                   const void* __restrict__ dtb,
                                                   const void* __restrict__ Alog,
                                                   const void* __restrict__ Dp,
                                                   const int* __restrict__ flagp) {
  int f = *flagp;
  int gid = blockIdx.x * NTHREADS + threadIdx.x;
  int d = gid & 127, n = gid >> 7;
  float A[16];
#pragma unroll
  for (int s = 0; s < 16; s++) A[s] = -__expf(fminf(ldf(Alog, d * 16 + s, f), 60.f));
  float W0 = ldf(dtw, d * 4 + 0, f), W1 = ldf(dtw, d * 4 + 1, f);
  float W2 = ldf(dtw, d * 4 + 2, f), W3 = ldf(dtw, d * 4 + 3, f);
  float bias = ldf(dtb, d, f);
  float Dv = ldf(Dp, d, f);
  float st[16];
#pragma unroll
  for (int s = 0; s < 16; s++) st[s] = 0.f;
  for (int z = 0; z < 32; z++) {
    size_t r = (size_t)(z << 12) | n;
    const __hip_bfloat16* bp = xdbl + r * 36;
    float v = bias;
    v = fmaf(bf2f(bp[0]), W0, v);
    v = fmaf(bf2f(bp[1]), W1, v);
    v = fmaf(bf2f(bp[2]), W2, v);
    v = fmaf(bf2f(bp[3]), W3, v);
    float dtv = v > 20.f ? v : log1pf(__expf(v));
    dtv = fminf(fmaxf(dtv, 0.f), 60.f);
    float u = sane(bf2f(uy[r * 128 + d]));
    float zv = sane(bf2f(zg[r * 128 + d]));
    float du = dtv * u;
    float y = 0.f;
#pragma unroll
    for (int s = 0; s < 16; s++) {
      float Bv = bf2f(bp[4 + s]);
      float Cv = bf2f(bp[20 + s]);
      st[s] = fmaf(__expf(dtv * A[s]), st[s], du * Bv);
      y = fmaf(st[s], Cv, y);
    }
    y = sane((y + Dv * u) * (zv * sigm(zv)));
    uy[r * 128 + d] = f2bf(y);
  }
}

// ---------------- W_comb = proj_w @ out_proj_w -> bf16 [o][d] ----------------
__global__ void k_wcomb(const void* __restrict__ pw, const void* __restrict__ opw,
                        __hip_bfloat16* __restrict__ wc, const int* __restrict__ flagp) {
  int f = *flagp;
  int gid = blockIdx.x * NTHREADS + threadIdx.x;
  int d = gid & 127, o = gid >> 7;
  float a = 0.f;
#pragma unroll
  for (int j = 0; j < 64; j++) a = fmaf(ldf(pw, o * 64 + j, f), ldf(opw, j * 128 + d, f), a);
  wc[(size_t)o * 128 + d] = f2bf(a);
}

// ---------------- out_proj+proj MFMA ----------------
__global__ __launch_bounds__(NTHREADS) void k_outproj_mfma(const __hip_bfloat16* __restrict__ A,
                                                           const __hip_bfloat16* __restrict__ Wcb,
                                                           const void* __restrict__ bias,
                                                           __hip_bfloat16* __restrict__ out,
                                                           const int* __restrict__ flagp) {
  __shared__ unsigned short Wl[64 * 136];
  __shared__ float bl[64];
  int f = *flagp;
  int t = threadIdx.x;
  const unsigned short* ws = (const unsigned short*)Wcb;
  for (int i = t; i < 8192; i += NTHREADS) Wl[(i >> 7) * 136 + (i & 127)] = ws[i];
  if (t < 64) bl[t] = ldf(bias, t, f);
  __syncthreads();
  int wv = t >> 6, lane = t & 63;
  int m = lane & 15, quad = lane >> 4;
  long m0 = (long)blockIdx.x * 256 + wv * 64;
  f4_t zero4 = {0.f, 0.f, 0.f, 0.f};
  f4_t acc[4][4];
#pragma unroll
  for (int mt = 0; mt < 4; mt++)
#pragma unroll
    for (int nt = 0; nt < 4; nt++) acc[mt][nt] = zero4;
  const unsigned short* ap = (const unsigned short*)A;
#pragma unroll
  for (int ch = 0; ch < 4; ch++) {
    int kof = ch * 32 + quad * 8;
    bs8_t a0 = *(const bs8_t*)(ap + (m0 + 0 * 16 + m) * 128 + kof);
    bs8_t a1 = *(const bs8_t*)(ap + (m0 + 1 * 16 + m) * 128 + kof);
    bs8_t a2 = *(const bs8_t*)(ap + (m0 + 2 * 16 + m) * 128 + kof);
    bs8_t a3 = *(const bs8_t*)(ap + (m0 + 3 * 16 + m) * 128 + kof);
#pragma unroll
    for (int nt = 0; nt < 4; nt++) {
      bs8_t b = *(const bs8_t*)&Wl[(nt * 16 + m) * 136 + kof];
      acc[0][nt] = __builtin_amdgcn_mfma_f32_16x16x32_bf16(a0, b, acc[0][nt], 0, 0, 0);
      acc[1][nt] = __builtin_amdgcn_mfma_f32_16x16x32_bf16(a1, b, acc[1][nt], 0, 0, 0);
      acc[2][nt] = __builtin_amdgcn_mfma_f32_16x16x32_bf16(a2, b, acc[2][nt], 0, 0, 0);
      acc[3][nt] = __builtin_amdgcn_mfma_f32_16x16x32_bf16(a3, b, acc[3][nt], 0, 0, 0);
    }
  }
#pragma unroll
  for (int mt = 0; mt < 4; mt++)
#pragma unroll
    for (int nt = 0; nt < 4; nt++) {
      int co = nt * 16 + m;
#pragma unroll
      for (int rg = 0; rg < 4; rg++) {
        long row = m0 + mt * 16 + quad * 4 + rg;
        out[row * 64 + co] = f2bf(sane(acc[mt][nt][rg] + bl[co]));
      }
    }
}

// ---------------- pn stats ----------------
__global__ __launch_bounds__(NTHREADS) void k_pnstats2(const __hip_bfloat16* __restrict__ s2,
                                                       float* __restrict__ acc) {
  __shared__ float rs[64], rq[64];
  int t = threadIdx.x;
  int c = t & 63;
  int sub = t >> 6;
  float s = 0.f, q = 0.f;
  size_t r0 = (size_t)blockIdx.x * 2048 + sub;
  for (int i = 0; i < 512; i++) {
    float v = sane(bf2f(s2[(r0 + (size_t)i * 4) * 64 + c]));
    s += v;
    q += v * v;
  }
  if (sub == 0) { rs[c] = 0.f; rq[c] = 0.f; }
  __syncthreads();
  for (int w = 0; w < 4; w++) {
    if (sub == w) { rs[c] += s; rq[c] += q; }
    __syncthreads();
  }
  if (t < 64) {
    atomicAdd(&acc[t], rs[t]);
    atomicAdd(&acc[64 + t], rq[t]);
  }
}

// ---------------- final ----------------
__global__ __launch_bounds__(NTHREADS) void k_final(const __hip_bfloat16* __restrict__ s2,
                                                    void* __restrict__ io,
                                                    const float* __restrict__ ss,
                                                    const int* __restrict__ flagp) {
  __shared__ float tile[64 * 65];
  __shared__ float sc[64], sh[64];
  int f = *flagp;
  int t = threadIdx.x;
  if (t < 64) {
    sc[t] = ss[t];
    sh[t] = ss[64 + t];
  }
  int z = blockIdx.x >> 6, n0 = (blockIdx.x & 63) << 6;
  size_t base = ((size_t)z * 4096 + n0) * 64;
  __syncthreads();
#pragma unroll
  for (int jj = 0; jj < 16; jj++) {
    int id = t + jj * NTHREADS;
    int i = id >> 6, c = id & 63;
    float v = sane(bf2f(s2[base + id]));
    tile[i * 65 + c] = sc[c] * v + sh[c];
  }
  __syncthreads();
#pragma unroll
  for (int jj = 0; jj < 16; jj++) {
    int id = t + jj * NTHREADS;
    int c = id >> 6, nl = id & 63;
    size_t off = (size_t)c * 131072 + (size_t)z * 4096 + n0 + nl;
    if (f) {
      float* o = (float*)io;
      o[off] = sane(o[off] + tile[nl * 65 + c]);
    } else {
      __hip_bfloat16* o = (__hip_bfloat16*)io;
      o[off] = f2bf(sane(bf2f(o[off]) + tile[nl * 65 + c]));
    }
  }
}

// ---------------- launch ----------------
extern "C" void kernel_launch(void* const* d_in, const int* in_sizes, int n_in,
                              void* d_out, int out_size, void* d_ws, size_t ws_size,
                              hipStream_t stream) {
  (void)in_sizes; (void)n_in; (void)out_size; (void)ws_size;
  const void* x        = d_in[0];
  const void* c1_w     = d_in[1];
  const void* in1_g    = d_in[2];
  const void* in1_b    = d_in[3];
  const void* c2_w     = d_in[4];
  const void* in2_g    = d_in[5];
  const void* in2_b    = d_in[6];
  const void* dw_w     = d_in[7];
  const void* pw_w     = d_in[8];
  const void* inr_g    = d_in[9];
  const void* inr_b    = d_in[10];
  const void* ln_g     = d_in[11];
  const void* ln_b     = d_in[12];
  const void* in_proj_w= d_in[13];
  const void* conv1d_w = d_in[14];
  const void* conv1d_b = d_in[15];
  const void* x_proj_w = d_in[16];
  const void* dt_proj_w= d_in[17];
  const void* dt_proj_b= d_in[18];
  const void* A_log    = d_in[19];
  const void* D_p      = d_in[20];
  const void* out_proj_w=d_in[21];
  const void* proj_w   = d_in[22];
  const void* proj_b   = d_in[23];
  const void* pn_g     = d_in[24];
  const void* pn_b     = d_in[25];

  char* wb = (char*)d_ws;
  // Byte layout, TOTAL ~= 85.3 MB (< 90.3 MB proven mapped in R7).
  // R0 [0, 33,554,432): P1(9.5M) -> P2(19.5M) -> zg(33.5M) -> s2(16.8M)
  __hip_bfloat16* P1   = (__hip_bfloat16*)wb;
  __hip_bfloat16* P2   = (__hip_bfloat16*)wb;
  __hip_bfloat16* zgb  = (__hip_bfloat16*)wb;
  __hip_bfloat16* s2   = (__hip_bfloat16*)wb;
  // R1 [33,554,432, 67,108,864): c1raw(17.3M) -> c2raw(17.8M) | pre2(16.8M) -> x_in(33.5M)
  __hip_bfloat16* c1raw = (__hip_bfloat16*)(wb + 33554432);
  __hip_bfloat16* c2raw = (__hip_bfloat16*)(wb + 33554432);
  __hip_bfloat16* pre2  = (__hip_bfloat16*)(wb + 33554432);
  __hip_bfloat16* x_in  = (__hip_bfloat16*)(wb + 33554432);
  // hcl [51,380,224, 68,157,440)
  __hip_bfloat16* hcl   = (__hip_bfloat16*)(wb + 51380224);
  // seq [68,157,440, 84,934,656); xdbl aliases seq after inproj
  __hip_bfloat16* seq   = (__hip_bfloat16*)(wb + 68157440);
  __hip_bfloat16* xdbl  = (__hip_bfloat16*)(wb + 68157440);
  // weights [84,934,656 ...)
  __hip_bfloat16* W1b   = (__hip_bfloat16*)(wb + 84934656);             // 73,728 B
  __hip_bfloat16* W2b   = (__hip_bfloat16*)(wb + 85008384);             // 147,456 B
  __hip_bfloat16* inwb  = (__hip_bfloat16*)(wb + 85155840);             // 32,768 B
  __hip_bfloat16* wcombb= (__hip_bfloat16*)(wb + 85188608);             // 16,384 B
  __hip_bfloat16* pwbb  = (__hip_bfloat16*)(wb + 85204992);             // 8,192 B
  __hip_bfloat16* xpwb  = (__hip_bfloat16*)(wb + 85213184);             // 9,216 B
  float*          fst   = (float*)(wb + 85222400);

  float* acc_in1 = fst;
  float* acc_in2 = fst + 128;
  float* acc_inr = fst + 256;
  float* acc_pn  = fst + 384;
  float* ss_in1  = fst + 512;
  float* ss_in2  = fst + 640;
  float* ss_inr  = fst + 768;
  float* ss_pn   = fst + 896;
  int*   flagp   = (int*)(fst + 1024);

  hipMemsetAsync(fst, 0, 512 * sizeof(float), stream);

  k_detect<<<1, NTHREADS, 0, stream>>>(x, flagp);
  k_pad1<<<34 * 66, NTHREADS, 0, stream>>>(x, P1, flagp);
  k_prepw<<<144, NTHREADS, 0, stream>>>(c1_w, W1b, 32, flagp);
  k_prepw<<<288, NTHREADS, 0, stream>>>(c2_w, W2b, 64, flagp);
  k_prepcvt<<<64, NTHREADS, 0, stream>>>(in_proj_w, inwb, 16384, flagp);
  k_prepcvt<<<16, NTHREADS, 0, stream>>>(pw_w, pwbb, 4096, flagp);
  k_prepcvt<<<18, NTHREADS, 0, stream>>>(x_proj_w, xpwb, 4608, flagp);
  k_wcomb<<<32, NTHREADS, 0, stream>>>(proj_w, out_proj_w, wcombb, flagp);

  k_gemm_conv<32, 40><<<33 * 16, NTHREADS, 0, stream>>>(P1, W1b, c1raw);
  k_stats_cl<<<256, NTHREADS, 0, stream>>>(c1raw, acc_in1, 528);
  k_finalize<<<1, 64, 0, stream>>>(acc_in1, in1_g, in1_b, ss_in1, 1.0f / 135168.0f, flagp);
  k_normpad<<<35 * 66, NTHREADS, 0, stream>>>(c1raw, ss_in1, P2);

  k_gemm_conv<64, 88><<<34 * 16, NTHREADS, 0, stream>>>(P2, W2b, c2raw);
  k_stats_cl<<<256, NTHREADS, 0, stream>>>(c2raw, acc_in2, 544);
  k_finalize<<<1, 64, 0, stream>>>(acc_in2, in2_g, in2_b, ss_in2, 1.0f / 139264.0f, flagp);
  k_hslice_cl<<<2048, NTHREADS, 0, stream>>>(c2raw, ss_in2, hcl, d_out, flagp);

  k_dwpw_mfma<<<2048, NTHREADS, 0, stream>>>(hcl, dw_w, pwbb, pre2, acc_inr, flagp);
  k_finalize<<<1, 64, 0, stream>>>(acc_inr, inr_g, inr_b, ss_inr, 1.0f / 131072.0f, flagp);
  k_x2ln_cl<<<512, NTHREADS, 0, stream>>>(hcl, pre2, ss_inr, ln_g, ln_b, seq, flagp);

  k_inproj_mfma<<<2048, NTHREADS, 0, stream>>>(seq, inwb, x_in, zgb);
  k_conv1d_ip<<<2048, NTHREADS, 0, stream>>>(x_in, conv1d_w, conv1d_b, flagp);
  k_xproj_mfma<<<512, NTHREADS, 0, stream>>>(x_in, xpwb, xdbl);
  k_scan<<<2048, NTHREADS, 0, stream>>>(xdbl, x_in, zgb, dt_proj_w, dt_proj_b, A_log, D_p, flagp);
  k_outproj_mfma<<<512, NTHREADS, 0, stream>>>(x_in, wcombb, proj_b, s2, flagp);

  k_pnstats2<<<64, NTHREADS, 0, stream>>>(s2, acc_pn);
  k_finalize<<<1, 64, 0, stream>>>(acc_pn, pn_g, pn_b, ss_pn, 1.0f / 131072.0f, flagp);
  k_final<<<2048, NTHREADS, 0, stream>>>(s2, d_out, ss_pn, flagp);
}